// Round 1
// baseline (288.700 us; speedup 1.0000x reference)
//
#include <hip/hip_runtime.h>
#include <hip/hip_bf16.h>

// Problem constants (fixed by reference)
#define NROWS 8192
#define HDIM  2048
#define EXP   8
#define RANK  8

typedef float  f32x4  __attribute__((ext_vector_type(4)));
typedef __bf16 bf16x8 __attribute__((ext_vector_type(8)));

// async global->LDS, 16B per lane; LDS dest must be wave-uniform (HW: base + lane*16)
__device__ __forceinline__ void gload_lds16(const void* g, void* l) {
  __builtin_amdgcn_global_load_lds((const __attribute__((address_space(1))) void*)g,
                                   (__attribute__((address_space(3))) void*)l, 16, 0, 0);
}

// ---------- K1: elementwise f32 -> bf16 cast (x) ----------
__global__ __launch_bounds__(256) void k_cast_bf16(const float* __restrict__ src,
                                                   __hip_bfloat16* __restrict__ dst) {
  size_t i = ((size_t)blockIdx.x * 256 + threadIdx.x) * 8;
  float4 a = *(const float4*)(src + i);
  float4 b = *(const float4*)(src + i + 4);
  union { __hip_bfloat16 h[8]; int4 v; } u;
  u.h[0] = __float2bfloat16(a.x); u.h[1] = __float2bfloat16(a.y);
  u.h[2] = __float2bfloat16(a.z); u.h[3] = __float2bfloat16(a.w);
  u.h[4] = __float2bfloat16(b.x); u.h[5] = __float2bfloat16(b.y);
  u.h[6] = __float2bfloat16(b.z); u.h[7] = __float2bfloat16(b.w);
  *(int4*)(dst + i) = u.v;
}

// ---------- K2: W1 [k][n] f32 -> W1T [n][k] bf16 (LDS-tiled transpose) ----------
__global__ __launch_bounds__(256) void k_transcast(const float* __restrict__ W,
                                                   __hip_bfloat16* __restrict__ WT) {
  __shared__ float s[64][65];
  int n0 = blockIdx.x * 64, k0 = blockIdx.y * 64;
  for (int i = 0; i < 16; ++i) {
    int idx = threadIdx.x + i * 256;
    int r = idx >> 6, c = idx & 63;
    s[r][c] = W[(size_t)(k0 + r) * HDIM + n0 + c];
  }
  __syncthreads();
  for (int i = 0; i < 16; ++i) {
    int idx = threadIdx.x + i * 256;
    int r = idx >> 6, c = idx & 63;
    WT[(size_t)(n0 + r) * HDIM + k0 + c] = __float2bfloat16(s[c][r]);
  }
}

// ---------- K2b: A [E][H][R] f32 -> AT [E*R][H] bf16 ----------
__global__ __launch_bounds__(256) void k_cast_A(const float* __restrict__ A,
                                                __hip_bfloat16* __restrict__ AT) {
  __shared__ float s[2048];                      // 256 h x 8 r
  int e = blockIdx.x >> 3, ht = blockIdx.x & 7;
  const float* src = A + (size_t)e * (HDIM * RANK) + (size_t)ht * 256 * RANK;
  for (int i = 0; i < 8; ++i) s[threadIdx.x + i * 256] = src[threadIdx.x + i * 256];
  __syncthreads();
  for (int i = 0; i < 8; ++i) {
    int idx = threadIdx.x + i * 256;
    int r = idx >> 8, hh = idx & 255;
    AT[(size_t)(e * RANK + r) * HDIM + ht * 256 + hh] = __float2bfloat16(s[hh * 8 + r]);
  }
}

// ---------- K3: h = relu(x @ W1 + b1), bf16 MFMA, 128x128 tile, BK=32 ----------
// m97-structure: single LDS buffer, global_load_lds w16, 4 waves of 64x64 (4x4 frags)
__global__ __launch_bounds__(256) void k_gemm_h(const __hip_bfloat16* __restrict__ X,
                                                const __hip_bfloat16* __restrict__ WT,
                                                const float* __restrict__ b1,
                                                __hip_bfloat16* __restrict__ Hb) {
  __shared__ __hip_bfloat16 As[128][32];   // 8KB
  __shared__ __hip_bfloat16 Bs[128][32];   // 8KB
  const int tid = threadIdx.x;
  const int wave = tid >> 6, lane = tid & 63;
  const int g = lane >> 4, c16 = lane & 15;
  const int m0 = blockIdx.y * 128, n0 = blockIdx.x * 128;
  const int wm = (wave >> 1) * 64, wn = (wave & 1) * 64;
  f32x4 acc[4][4] = {};
  const int srow = wave * 32 + (lane >> 2);
  const int scol = (lane & 3) * 8;
  const __hip_bfloat16* ga = X  + (size_t)(m0 + srow) * HDIM + scol;
  const __hip_bfloat16* gb = WT + (size_t)(n0 + srow) * HDIM + scol;
  for (int k0 = 0; k0 < HDIM; k0 += 32) {
    __syncthreads();                         // all waves done reading LDS
    gload_lds16(ga + k0,             &As[wave * 32][0]);
    gload_lds16(ga + k0 + 16 * HDIM, &As[wave * 32 + 16][0]);
    gload_lds16(gb + k0,             &Bs[wave * 32][0]);
    gload_lds16(gb + k0 + 16 * HDIM, &Bs[wave * 32 + 16][0]);
    __syncthreads();                         // drains vmcnt -> tiles visible
    bf16x8 af[4], bfr[4];
#pragma unroll
    for (int i = 0; i < 4; ++i) af[i]  = *(const bf16x8*)&As[wm + i * 16 + c16][g * 8];
#pragma unroll
    for (int j = 0; j < 4; ++j) bfr[j] = *(const bf16x8*)&Bs[wn + j * 16 + c16][g * 8];
#pragma unroll
    for (int i = 0; i < 4; ++i)
#pragma unroll
      for (int j = 0; j < 4; ++j)
        acc[i][j] = __builtin_amdgcn_mfma_f32_16x16x32_bf16(af[i], bfr[j], acc[i][j], 0, 0, 0);
  }
  // D layout (verified): col = lane&15, row = 4*(lane>>4) + r
#pragma unroll
  for (int i = 0; i < 4; ++i)
#pragma unroll
    for (int j = 0; j < 4; ++j) {
      int col = n0 + wn + j * 16 + c16;
      float bias = b1[col];
#pragma unroll
      for (int r = 0; r < 4; ++r) {
        int row = m0 + wm + i * 16 + g * 4 + r;
        float v = acc[i][j][r] + bias;
        Hb[(size_t)row * HDIM + col] = __float2bfloat16(v > 0.f ? v : 0.f);
      }
    }
}

// ---------- K4: router w = softmax(h @ W2 + b2), one wave per row ----------
__global__ __launch_bounds__(256) void k_router(const __hip_bfloat16* __restrict__ Hb,
                                                const float* __restrict__ W2,
                                                const float* __restrict__ b2,
                                                float* __restrict__ wout) {
  const int wave = threadIdx.x >> 6, lane = threadIdx.x & 63;
  const int n = blockIdx.x * 4 + wave;
  float acc[8] = {0, 0, 0, 0, 0, 0, 0, 0};
  for (int it = 0; it < HDIM / 512; ++it) {
    int h0 = it * 512 + lane * 8;
    bf16x8 xv = *(const bf16x8*)&Hb[(size_t)n * HDIM + h0];
#pragma unroll
    for (int j = 0; j < 8; ++j) {
      float xf = (float)xv[j];
      const float4* wr = (const float4*)&W2[(size_t)(h0 + j) * EXP];
      float4 wa = wr[0], wb = wr[1];
      acc[0] += xf * wa.x; acc[1] += xf * wa.y; acc[2] += xf * wa.z; acc[3] += xf * wa.w;
      acc[4] += xf * wb.x; acc[5] += xf * wb.y; acc[6] += xf * wb.z; acc[7] += xf * wb.w;
    }
  }
#pragma unroll
  for (int off = 32; off; off >>= 1)
#pragma unroll
    for (int e = 0; e < 8; ++e) acc[e] += __shfl_xor(acc[e], off, 64);
  float lg[8], m = -1e30f;
#pragma unroll
  for (int e = 0; e < 8; ++e) { lg[e] = acc[e] + b2[e]; m = fmaxf(m, lg[e]); }
  float s = 0.f;
#pragma unroll
  for (int e = 0; e < 8; ++e) { lg[e] = __expf(lg[e] - m); s += lg[e]; }
  float inv = 1.f / s;
  if (lane < 8) wout[(size_t)n * EXP + lane] = lg[lane] * inv;
}

// ---------- K5: t partials = x @ AT^T, bf16 MFMA, 128x64 tile, K split x4 ----------
__global__ __launch_bounds__(256) void k_gemm_t(const __hip_bfloat16* __restrict__ X,
                                                const __hip_bfloat16* __restrict__ AT,
                                                float* __restrict__ tp) {
  __shared__ __hip_bfloat16 As[128][32];
  __shared__ __hip_bfloat16 Bs[64][32];
  const int tid = threadIdx.x;
  const int wave = tid >> 6, lane = tid & 63;
  const int g = lane >> 4, c16 = lane & 15;
  const int m0 = blockIdx.x * 128;
  const int kc = blockIdx.y;                 // K chunk of 512
  const int wm = (wave >> 1) * 64, wn = (wave & 1) * 32;
  f32x4 acc[4][2] = {};
  const int scol = (lane & 3) * 8;
  const __hip_bfloat16* ga = X  + (size_t)(m0 + wave * 32 + (lane >> 2)) * HDIM + scol;
  const __hip_bfloat16* gb = AT + (size_t)(wave * 16 + (lane >> 2)) * HDIM + scol;
  for (int k0 = kc * 512; k0 < kc * 512 + 512; k0 += 32) {
    __syncthreads();
    gload_lds16(ga + k0,             &As[wave * 32][0]);
    gload_lds16(ga + k0 + 16 * HDIM, &As[wave * 32 + 16][0]);
    gload_lds16(gb + k0,             &Bs[wave * 16][0]);
    __syncthreads();
    bf16x8 af[4], bfr[2];
#pragma unroll
    for (int i = 0; i < 4; ++i) af[i]  = *(const bf16x8*)&As[wm + i * 16 + c16][g * 8];
#pragma unroll
    for (int j = 0; j < 2; ++j) bfr[j] = *(const bf16x8*)&Bs[wn + j * 16 + c16][g * 8];
#pragma unroll
    for (int i = 0; i < 4; ++i)
#pragma unroll
      for (int j = 0; j < 2; ++j)
        acc[i][j] = __builtin_amdgcn_mfma_f32_16x16x32_bf16(af[i], bfr[j], acc[i][j], 0, 0, 0);
  }
#pragma unroll
  for (int i = 0; i < 4; ++i)
#pragma unroll
    for (int j = 0; j < 2; ++j)
#pragma unroll
      for (int r = 0; r < 4; ++r) {
        int row = m0 + wm + i * 16 + g * 4 + r;
        int col = wn + j * 16 + c16;
        tp[((size_t)kc * NROWS + row) * 64 + col] = acc[i][j][r];
      }
}

// ---------- K6: out[n][h] = sum_er (w[n][er/8]*t[n][er]) * B[er][h], fp32 ----------
__global__ __launch_bounds__(256) void k_final(const float* __restrict__ tp,
                                               const float* __restrict__ wgt,
                                               const float* __restrict__ Bm,
                                               float* __restrict__ out) {
  __shared__ float cs[32][64];
  const int t = threadIdx.x;
  const int n0 = blockIdx.x * 32;
  for (int i = 0; i < 8; ++i) {
    int idx = t + i * 256;
    int row = idx >> 6, er = idx & 63;
    size_t o = (size_t)(n0 + row) * 64 + er;
    const size_t CH = (size_t)NROWS * 64;
    float s = tp[o] + tp[o + CH] + tp[o + 2 * CH] + tp[o + 3 * CH];
    cs[row][er] = s * wgt[(size_t)(n0 + row) * EXP + (er >> 3)];
  }
  __syncthreads();
  const int rowgrp = t >> 5;   // 4 rows each
  const int colgrp = t & 31;   // 8 cols each per 256-chunk
  for (int cb = 0; cb < 8; ++cb) {
    int col0 = cb * 256 + colgrp * 8;
    f32x4 acc0[4] = {}, acc1[4] = {};
    for (int er = 0; er < 64; ++er) {
      f32x4 b0 = *(const f32x4*)&Bm[(size_t)er * HDIM + col0];
      f32x4 b1v = *(const f32x4*)&Bm[(size_t)er * HDIM + col0 + 4];
#pragma unroll
      for (int r = 0; r < 4; ++r) {
        float cv = cs[rowgrp * 4 + r][er];
        acc0[r] += cv * b0;
        acc1[r] += cv * b1v;
      }
    }
#pragma unroll
    for (int r = 0; r < 4; ++r) {
      size_t o = (size_t)(n0 + rowgrp * 4 + r) * HDIM + col0;
      *(f32x4*)&out[o] = acc0[r];
      *(f32x4*)&out[o + 4] = acc1[r];
    }
  }
}

extern "C" void kernel_launch(void* const* d_in, const int* in_sizes, int n_in,
                              void* d_out, int out_size, void* d_ws, size_t ws_size,
                              hipStream_t stream) {
  const float* x  = (const float*)d_in[0];
  const float* W1 = (const float*)d_in[1];
  const float* b1 = (const float*)d_in[2];
  const float* W2 = (const float*)d_in[3];
  const float* b2 = (const float*)d_in[4];
  const float* A  = (const float*)d_in[5];
  const float* B  = (const float*)d_in[6];
  float* out = (float*)d_out;

  char* ws = (char*)d_ws;
  // ws layout (bytes):
  //   xb   [8192*2048] bf16 : 33,554,432
  //   w1t  [2048*2048] bf16 :  8,388,608
  //   hb   [8192*2048] bf16 : 33,554,432
  //   at   [64*2048]   bf16 :    262,144
  //   wgt  [8192*8]    f32  :    262,144
  //   tp   [4*8192*64] f32  :  8,388,608   -> total 84,410,368
  __hip_bfloat16* xb  = (__hip_bfloat16*)(ws);
  __hip_bfloat16* w1t = (__hip_bfloat16*)(ws + 33554432);
  __hip_bfloat16* hb  = (__hip_bfloat16*)(ws + 41943040);
  __hip_bfloat16* at  = (__hip_bfloat16*)(ws + 75497472);
  float* wgt          = (float*)(ws + 75759616);
  float* tp           = (float*)(ws + 76021760);
  if (ws_size < 84410368) return;  // insufficient scratch -> will fail loudly

  k_cast_bf16<<<NROWS * HDIM / (256 * 8), 256, 0, stream>>>(x, xb);
  k_transcast<<<dim3(HDIM / 64, HDIM / 64), 256, 0, stream>>>(W1, w1t);
  k_cast_A<<<EXP * 8, 256, 0, stream>>>(A, at);
  k_gemm_h<<<dim3(HDIM / 128, NROWS / 128), 256, 0, stream>>>(xb, w1t, b1, hb);
  k_router<<<NROWS / 4, 256, 0, stream>>>(hb, W2, b2, wgt);
  k_gemm_t<<<dim3(NROWS / 128, 4), 256, 0, stream>>>(xb, at, tp);
  k_final<<<NROWS / 32, 256, 0, stream>>>(tp, wgt, B, out);
}

// Round 2
// 249.128 us; speedup vs baseline: 1.1588x; 1.1588x over previous
//
#include <hip/hip_runtime.h>
#include <hip/hip_bf16.h>

// Problem constants (fixed by reference)
#define NROWS 8192
#define HDIM  2048
#define EXP   8
#define RANK  8

typedef float  f32x4  __attribute__((ext_vector_type(4)));
typedef __bf16 bf16x8 __attribute__((ext_vector_type(8)));

// async global->LDS, 16B per lane; LDS dest must be wave-uniform (HW: base + lane*16)
__device__ __forceinline__ void gload_lds16(const void* g, void* l) {
  __builtin_amdgcn_global_load_lds((const __attribute__((address_space(1))) void*)g,
                                   (__attribute__((address_space(3))) void*)l, 16, 0, 0);
}

// ---------- K1: elementwise f32 -> bf16 cast (x) ----------
__global__ __launch_bounds__(256) void k_cast_bf16(const float* __restrict__ src,
                                                   __hip_bfloat16* __restrict__ dst) {
  size_t i = ((size_t)blockIdx.x * 256 + threadIdx.x) * 8;
  float4 a = *(const float4*)(src + i);
  float4 b = *(const float4*)(src + i + 4);
  union { __hip_bfloat16 h[8]; int4 v; } u;
  u.h[0] = __float2bfloat16(a.x); u.h[1] = __float2bfloat16(a.y);
  u.h[2] = __float2bfloat16(a.z); u.h[3] = __float2bfloat16(a.w);
  u.h[4] = __float2bfloat16(b.x); u.h[5] = __float2bfloat16(b.y);
  u.h[6] = __float2bfloat16(b.z); u.h[7] = __float2bfloat16(b.w);
  *(int4*)(dst + i) = u.v;
}

// ---------- K2: W1 [k][n] f32 -> W1T [n][k] bf16 (LDS-tiled transpose) ----------
__global__ __launch_bounds__(256) void k_transcast(const float* __restrict__ W,
                                                   __hip_bfloat16* __restrict__ WT) {
  __shared__ float s[64][65];
  int n0 = blockIdx.x * 64, k0 = blockIdx.y * 64;
  for (int i = 0; i < 16; ++i) {
    int idx = threadIdx.x + i * 256;
    int r = idx >> 6, c = idx & 63;
    s[r][c] = W[(size_t)(k0 + r) * HDIM + n0 + c];
  }
  __syncthreads();
  for (int i = 0; i < 16; ++i) {
    int idx = threadIdx.x + i * 256;
    int r = idx >> 6, c = idx & 63;
    WT[(size_t)(n0 + r) * HDIM + k0 + c] = __float2bfloat16(s[c][r]);
  }
}

// ---------- K2b: A [E][H][R] f32 -> AT [E*R][H] bf16 ----------
__global__ __launch_bounds__(256) void k_cast_A(const float* __restrict__ A,
                                                __hip_bfloat16* __restrict__ AT) {
  __shared__ float s[2048];                      // 256 h x 8 r
  int e = blockIdx.x >> 3, ht = blockIdx.x & 7;
  const float* src = A + (size_t)e * (HDIM * RANK) + (size_t)ht * 256 * RANK;
  for (int i = 0; i < 8; ++i) s[threadIdx.x + i * 256] = src[threadIdx.x + i * 256];
  __syncthreads();
  for (int i = 0; i < 8; ++i) {
    int idx = threadIdx.x + i * 256;
    int r = idx >> 8, hh = idx & 255;
    AT[(size_t)(e * RANK + r) * HDIM + ht * 256 + hh] = __float2bfloat16(s[hh * 8 + r]);
  }
}

// ---------- K3: h = relu(x @ W1 + b1), bf16 MFMA, 128x128 tile, BK=32 ----------
// m97-structure: single LDS buffer, global_load_lds w16, 4 waves of 64x64 (4x4 frags)
__global__ __launch_bounds__(256) void k_gemm_h(const __hip_bfloat16* __restrict__ X,
                                                const __hip_bfloat16* __restrict__ WT,
                                                const float* __restrict__ b1,
                                                __hip_bfloat16* __restrict__ Hb) {
  __shared__ __hip_bfloat16 As[128][32];   // 8KB
  __shared__ __hip_bfloat16 Bs[128][32];   // 8KB
  const int tid = threadIdx.x;
  const int wave = tid >> 6, lane = tid & 63;
  const int g = lane >> 4, c16 = lane & 15;
  const int m0 = blockIdx.y * 128, n0 = blockIdx.x * 128;
  const int wm = (wave >> 1) * 64, wn = (wave & 1) * 64;
  f32x4 acc[4][4] = {};
  const int srow = wave * 32 + (lane >> 2);
  const int scol = (lane & 3) * 8;
  const __hip_bfloat16* ga = X  + (size_t)(m0 + srow) * HDIM + scol;
  const __hip_bfloat16* gb = WT + (size_t)(n0 + srow) * HDIM + scol;
  for (int k0 = 0; k0 < HDIM; k0 += 32) {
    __syncthreads();                         // all waves done reading LDS
    gload_lds16(ga + k0,             &As[wave * 32][0]);
    gload_lds16(ga + k0 + 16 * HDIM, &As[wave * 32 + 16][0]);
    gload_lds16(gb + k0,             &Bs[wave * 32][0]);
    gload_lds16(gb + k0 + 16 * HDIM, &Bs[wave * 32 + 16][0]);
    __syncthreads();                         // drains vmcnt -> tiles visible
    bf16x8 af[4], bfr[4];
#pragma unroll
    for (int i = 0; i < 4; ++i) af[i]  = *(const bf16x8*)&As[wm + i * 16 + c16][g * 8];
#pragma unroll
    for (int j = 0; j < 4; ++j) bfr[j] = *(const bf16x8*)&Bs[wn + j * 16 + c16][g * 8];
#pragma unroll
    for (int i = 0; i < 4; ++i)
#pragma unroll
      for (int j = 0; j < 4; ++j)
        acc[i][j] = __builtin_amdgcn_mfma_f32_16x16x32_bf16(af[i], bfr[j], acc[i][j], 0, 0, 0);
  }
  // D layout (verified): col = lane&15, row = 4*(lane>>4) + r
#pragma unroll
  for (int i = 0; i < 4; ++i)
#pragma unroll
    for (int j = 0; j < 4; ++j) {
      int col = n0 + wn + j * 16 + c16;
      float bias = b1[col];
#pragma unroll
      for (int r = 0; r < 4; ++r) {
        int row = m0 + wm + i * 16 + g * 4 + r;
        float v = acc[i][j][r] + bias;
        Hb[(size_t)row * HDIM + col] = __float2bfloat16(v > 0.f ? v : 0.f);
      }
    }
}

// ---------- K4: router w = softmax(h @ W2 + b2), one wave per row ----------
__global__ __launch_bounds__(256) void k_router(const __hip_bfloat16* __restrict__ Hb,
                                                const float* __restrict__ W2,
                                                const float* __restrict__ b2,
                                                float* __restrict__ wout) {
  const int wave = threadIdx.x >> 6, lane = threadIdx.x & 63;
  const int n = blockIdx.x * 4 + wave;
  float acc[8] = {0, 0, 0, 0, 0, 0, 0, 0};
  for (int it = 0; it < HDIM / 512; ++it) {
    int h0 = it * 512 + lane * 8;
    bf16x8 xv = *(const bf16x8*)&Hb[(size_t)n * HDIM + h0];
#pragma unroll
    for (int j = 0; j < 8; ++j) {
      float xf = (float)xv[j];
      const float4* wr = (const float4*)&W2[(size_t)(h0 + j) * EXP];
      float4 wa = wr[0], wb = wr[1];
      acc[0] += xf * wa.x; acc[1] += xf * wa.y; acc[2] += xf * wa.z; acc[3] += xf * wa.w;
      acc[4] += xf * wb.x; acc[5] += xf * wb.y; acc[6] += xf * wb.z; acc[7] += xf * wb.w;
    }
  }
#pragma unroll
  for (int off = 32; off; off >>= 1)
#pragma unroll
    for (int e = 0; e < 8; ++e) acc[e] += __shfl_xor(acc[e], off, 64);
  float lg[8], m = -1e30f;
#pragma unroll
  for (int e = 0; e < 8; ++e) { lg[e] = acc[e] + b2[e]; m = fmaxf(m, lg[e]); }
  float s = 0.f;
#pragma unroll
  for (int e = 0; e < 8; ++e) { lg[e] = __expf(lg[e] - m); s += lg[e]; }
  float inv = 1.f / s;
  if (lane < 8) wout[(size_t)n * EXP + lane] = lg[lane] * inv;
}

// ---------- K5: t partials = x @ AT^T, bf16 MFMA, 128x64 tile, K split x4 ----------
__global__ __launch_bounds__(256) void k_gemm_t(const __hip_bfloat16* __restrict__ X,
                                                const __hip_bfloat16* __restrict__ AT,
                                                float* __restrict__ tp) {
  __shared__ __hip_bfloat16 As[128][32];
  __shared__ __hip_bfloat16 Bs[64][32];
  const int tid = threadIdx.x;
  const int wave = tid >> 6, lane = tid & 63;
  const int g = lane >> 4, c16 = lane & 15;
  const int m0 = blockIdx.x * 128;
  const int kc = blockIdx.y;                 // K chunk of 512
  const int wm = (wave >> 1) * 64, wn = (wave & 1) * 32;
  f32x4 acc[4][2] = {};
  const int scol = (lane & 3) * 8;
  const __hip_bfloat16* ga = X  + (size_t)(m0 + wave * 32 + (lane >> 2)) * HDIM + scol;
  const __hip_bfloat16* gb = AT + (size_t)(wave * 16 + (lane >> 2)) * HDIM + scol;
  for (int k0 = kc * 512; k0 < kc * 512 + 512; k0 += 32) {
    __syncthreads();
    gload_lds16(ga + k0,             &As[wave * 32][0]);
    gload_lds16(ga + k0 + 16 * HDIM, &As[wave * 32 + 16][0]);
    gload_lds16(gb + k0,             &Bs[wave * 16][0]);
    __syncthreads();
    bf16x8 af[4], bfr[2];
#pragma unroll
    for (int i = 0; i < 4; ++i) af[i]  = *(const bf16x8*)&As[wm + i * 16 + c16][g * 8];
#pragma unroll
    for (int j = 0; j < 2; ++j) bfr[j] = *(const bf16x8*)&Bs[wn + j * 16 + c16][g * 8];
#pragma unroll
    for (int i = 0; i < 4; ++i)
#pragma unroll
      for (int j = 0; j < 2; ++j)
        acc[i][j] = __builtin_amdgcn_mfma_f32_16x16x32_bf16(af[i], bfr[j], acc[i][j], 0, 0, 0);
  }
#pragma unroll
  for (int i = 0; i < 4; ++i)
#pragma unroll
    for (int j = 0; j < 2; ++j)
#pragma unroll
      for (int r = 0; r < 4; ++r) {
        int row = m0 + wm + i * 16 + g * 4 + r;
        int col = wn + j * 16 + c16;
        tp[((size_t)kc * NROWS + row) * 64 + col] = acc[i][j][r];
      }
}

// ---------- K5b: c[n][er] = (sum_kc tp) * w[n][er>>3], written IN PLACE over
// tp chunk 0 (each thread reads exactly the elements it overwrites -> race-free)
__global__ __launch_bounds__(256) void k_combine(float* __restrict__ tp,
                                                 const float* __restrict__ wgt) {
  size_t i = ((size_t)blockIdx.x * 256 + threadIdx.x) * 4;
  const size_t CH = (size_t)NROWS * 64;
  f32x4 s = *(const f32x4*)(tp + i);
  s += *(const f32x4*)(tp + i + CH);
  s += *(const f32x4*)(tp + i + 2 * CH);
  s += *(const f32x4*)(tp + i + 3 * CH);
  size_t n = i >> 6;
  int er = (int)(i & 63);                 // multiple of 4 -> same expert for all 4
  float w = wgt[n * EXP + (er >> 3)];
  *(f32x4*)(tp + i) = s * w;
}

// ---------- K6: out[n][h] = sum_er c[n][er] * B[er][h], fp32 VALU ----------
// 32 rows x 256 cols per block -> 2048 blocks = 8 blocks/CU (was 256 = 1/CU)
__global__ __launch_bounds__(256) void k_final(const float* __restrict__ c,
                                               const float* __restrict__ Bm,
                                               float* __restrict__ out) {
  __shared__ float cs[32][64];
  const int t = threadIdx.x;
  const int n0 = (blockIdx.x >> 3) * 32;
  const int col0 = (blockIdx.x & 7) * 256;
  {
    int idx = t * 8;                      // 2048 floats = 256 threads x 8
    const float* src = c + (size_t)n0 * 64 + idx;
    *(f32x4*)&cs[idx >> 6][idx & 63] = *(const f32x4*)src;
    *(f32x4*)&cs[(idx + 4) >> 6][(idx + 4) & 63] = *(const f32x4*)(src + 4);
  }
  __syncthreads();
  const int rg = t >> 5;                  // 8 groups of 4 rows
  const int cg = t & 31;                  // 32 groups of 8 cols
  const int cc = col0 + cg * 8;
  f32x4 acc0[4] = {}, acc1[4] = {};
#pragma unroll 4
  for (int er = 0; er < 64; ++er) {
    f32x4 b0  = *(const f32x4*)&Bm[(size_t)er * HDIM + cc];
    f32x4 b1v = *(const f32x4*)&Bm[(size_t)er * HDIM + cc + 4];
#pragma unroll
    for (int r = 0; r < 4; ++r) {
      float cv = cs[rg * 4 + r][er];      // wave-uniform per 32-lane half -> broadcast
      acc0[r] += cv * b0;
      acc1[r] += cv * b1v;
    }
  }
#pragma unroll
  for (int r = 0; r < 4; ++r) {
    size_t o = (size_t)(n0 + rg * 4 + r) * HDIM + cc;
    *(f32x4*)&out[o] = acc0[r];
    *(f32x4*)&out[o + 4] = acc1[r];
  }
}

extern "C" void kernel_launch(void* const* d_in, const int* in_sizes, int n_in,
                              void* d_out, int out_size, void* d_ws, size_t ws_size,
                              hipStream_t stream) {
  const float* x  = (const float*)d_in[0];
  const float* W1 = (const float*)d_in[1];
  const float* b1 = (const float*)d_in[2];
  const float* W2 = (const float*)d_in[3];
  const float* b2 = (const float*)d_in[4];
  const float* A  = (const float*)d_in[5];
  const float* B  = (const float*)d_in[6];
  float* out = (float*)d_out;

  char* ws = (char*)d_ws;
  // ws layout (bytes):
  //   xb   [8192*2048] bf16 : 33,554,432
  //   w1t  [2048*2048] bf16 :  8,388,608
  //   hb   [8192*2048] bf16 : 33,554,432
  //   at   [64*2048]   bf16 :    262,144
  //   wgt  [8192*8]    f32  :    262,144
  //   tp   [4*8192*64] f32  :  8,388,608   -> total 84,410,368
  __hip_bfloat16* xb  = (__hip_bfloat16*)(ws);
  __hip_bfloat16* w1t = (__hip_bfloat16*)(ws + 33554432);
  __hip_bfloat16* hb  = (__hip_bfloat16*)(ws + 41943040);
  __hip_bfloat16* at  = (__hip_bfloat16*)(ws + 75497472);
  float* wgt          = (float*)(ws + 75759616);
  float* tp           = (float*)(ws + 76021760);
  if (ws_size < 84410368) return;  // insufficient scratch -> will fail loudly

  k_cast_bf16<<<NROWS * HDIM / (256 * 8), 256, 0, stream>>>(x, xb);
  k_transcast<<<dim3(HDIM / 64, HDIM / 64), 256, 0, stream>>>(W1, w1t);
  k_cast_A<<<EXP * 8, 256, 0, stream>>>(A, at);
  k_gemm_h<<<dim3(HDIM / 128, NROWS / 128), 256, 0, stream>>>(xb, w1t, b1, hb);
  k_router<<<NROWS / 4, 256, 0, stream>>>(hb, W2, b2, wgt);
  k_gemm_t<<<dim3(NROWS / 128, 4), 256, 0, stream>>>(xb, at, tp);
  k_combine<<<NROWS * 64 / (256 * 4), 256, 0, stream>>>(tp, wgt);
  k_final<<<2048, 256, 0, stream>>>(tp /*=c*/, B, out);
}

// Round 3
// 221.389 us; speedup vs baseline: 1.3040x; 1.1253x over previous
//
#include <hip/hip_runtime.h>
#include <hip/hip_bf16.h>

// Problem constants (fixed by reference)
#define NROWS 8192
#define HDIM  2048
#define EXP   8
#define RANK  8

typedef float  f32x4  __attribute__((ext_vector_type(4)));
typedef __bf16 bf16x8 __attribute__((ext_vector_type(8)));

// async global->LDS, 16B per lane; LDS dest must be wave-uniform (HW: base + lane*16)
__device__ __forceinline__ void gload_lds16(const void* g, void* l) {
  __builtin_amdgcn_global_load_lds((const __attribute__((address_space(1))) void*)g,
                                   (__attribute__((address_space(3))) void*)l, 16, 0, 0);
}

#define FENCE asm volatile("" ::: "memory")
// mid-phase sync: staged data (issued >=4 phases ago) is now visible to all waves
#define SYNC_MID6 do { FENCE; asm volatile("s_waitcnt vmcnt(6)" ::: "memory"); \
  __builtin_amdgcn_s_barrier(); __builtin_amdgcn_sched_barrier(0); FENCE; } while (0)
// end-phase sync: all waves' LDS reads of this phase are done (reads precede own MFMA
// via compiler lgkmcnt; MFMA precedes this barrier)
#define SYNC_END do { FENCE; __builtin_amdgcn_sched_barrier(0); \
  __builtin_amdgcn_s_barrier(); __builtin_amdgcn_sched_barrier(0); FENCE; } while (0)

// ---------- K1: elementwise f32 -> bf16 cast (x) ----------
__global__ __launch_bounds__(256) void k_cast_bf16(const float* __restrict__ src,
                                                   __hip_bfloat16* __restrict__ dst) {
  size_t i = ((size_t)blockIdx.x * 256 + threadIdx.x) * 8;
  float4 a = *(const float4*)(src + i);
  float4 b = *(const float4*)(src + i + 4);
  union { __hip_bfloat16 h[8]; int4 v; } u;
  u.h[0] = __float2bfloat16(a.x); u.h[1] = __float2bfloat16(a.y);
  u.h[2] = __float2bfloat16(a.z); u.h[3] = __float2bfloat16(a.w);
  u.h[4] = __float2bfloat16(b.x); u.h[5] = __float2bfloat16(b.y);
  u.h[6] = __float2bfloat16(b.z); u.h[7] = __float2bfloat16(b.w);
  *(int4*)(dst + i) = u.v;
}

// ---------- K2: W1 [k][n] f32 -> W1T [n][k] bf16 (LDS-tiled transpose) ----------
__global__ __launch_bounds__(256) void k_transcast(const float* __restrict__ W,
                                                   __hip_bfloat16* __restrict__ WT) {
  __shared__ float s[64][65];
  int n0 = blockIdx.x * 64, k0 = blockIdx.y * 64;
  for (int i = 0; i < 16; ++i) {
    int idx = threadIdx.x + i * 256;
    int r = idx >> 6, c = idx & 63;
    s[r][c] = W[(size_t)(k0 + r) * HDIM + n0 + c];
  }
  __syncthreads();
  for (int i = 0; i < 16; ++i) {
    int idx = threadIdx.x + i * 256;
    int r = idx >> 6, c = idx & 63;
    WT[(size_t)(n0 + r) * HDIM + k0 + c] = __float2bfloat16(s[c][r]);
  }
}

// ---------- K2b: A [E][H][R] f32 -> AT [E*R][H] bf16 ----------
__global__ __launch_bounds__(256) void k_cast_A(const float* __restrict__ A,
                                                __hip_bfloat16* __restrict__ AT) {
  __shared__ float s[2048];                      // 256 h x 8 r
  int e = blockIdx.x >> 3, ht = blockIdx.x & 7;
  const float* src = A + (size_t)e * (HDIM * RANK) + (size_t)ht * 256 * RANK;
  for (int i = 0; i < 8; ++i) s[threadIdx.x + i * 256] = src[threadIdx.x + i * 256];
  __syncthreads();
  for (int i = 0; i < 8; ++i) {
    int idx = threadIdx.x + i * 256;
    int r = idx >> 8, hh = idx & 255;
    AT[(size_t)(e * RANK + r) * HDIM + ht * 256 + hh] = __float2bfloat16(s[hh * 8 + r]);
  }
}

// ---------- K3: h = relu(x @ W1 + b1) -- 256x256 8-phase MFMA template ----------
// 8 waves (2M x 4N), BK=64, 128KB LDS (2 dbuf x 2 half x 128 x 64 x bf16 x {A,B}),
// st_16x32 swizzle (byte ^= ((byte>>9)&1)<<5) on stage-source + ds_read,
// counted vmcnt(6) per phase (3 half-tiles in flight), setprio around MFMA.
// Phase/stage schedule (tile t, buf b=t&1):
//   P1: read A fr0-3 + B fc0-1 (12 ds_read) | stage A-lo(t+1) | MFMA q(r0-3,c0-1)
//   P2: read B fc2-3 (4)                    | stage A-hi(t+1) | MFMA q(r0-3,c2-3)
//   P3: read A fr4-7 (8)                    | stage B-lo(t+2) | MFMA q(r4-7,c2-3)
//   P4: (no reads, B kept in regs)          | stage B-hi(t+2) | MFMA q(r4-7,c0-1)
// Region-free proof: B(t) LDS free after P2 (staged P3/P4), A(t) free after P3
// (staged next tile's P1/P2). Every stage->consume gap >= 4 phases => vmcnt(6) valid.
__global__ __launch_bounds__(512, 2) void k_gemm_h8(const __hip_bfloat16* __restrict__ X,
                                                    const __hip_bfloat16* __restrict__ WT,
                                                    const float* __restrict__ b1,
                                                    __hip_bfloat16* __restrict__ Hb) {
  extern __shared__ char lds[];
  char* ldsA = lds;                 // [2 buf][2 half][128 rows][64 k] bf16 = 64KB
  char* ldsB = lds + 65536;         // same, rows = N-cols (WT is [n][k])
  const int tid = threadIdx.x;
  const int wid = tid >> 6, lane = tid & 63;
  const int wr = wid >> 2, wc = wid & 3;        // 2 x 4 wave grid
  const int g = lane >> 4, c16 = lane & 15;
  const int xm = (c16 & 4) << 3;                // read-side swizzle XOR (bit9 of L = bit2 of c16)
  const int m0 = blockIdx.y * 256, n0 = blockIdx.x * 256;
  const int NT = HDIM / 64;                     // 32 K-tiles

  // stage-source geometry (inverse st_16x32 swizzle; same for A and B)
  int srow[2], scol[2];
#pragma unroll
  for (int q = 0; q < 2; ++q) {
    int L = (q * 512 + tid) * 16;
    int s = L ^ (((L >> 9) & 1) << 5);
    srow[q] = s >> 7;
    scol[q] = (s & 127) >> 1;
  }
  auto stage = [&](const __hip_bfloat16* gb, int rowBase, int kBase, char* half) {
    gload_lds16(gb + (size_t)(rowBase + srow[0]) * HDIM + kBase + scol[0], half + tid * 16);
    gload_lds16(gb + (size_t)(rowBase + srow[1]) * HDIM + kBase + scol[1], half + 8192 + tid * 16);
  };
  auto ldA = [&](int b, int fr, int ks) -> bf16x8 {
    int byte = (((fr << 4) + c16) << 7) + (ks << 6) + (g << 4);
    return *(const bf16x8*)(ldsA + b * 32768 + wr * 16384 + (byte ^ xm));
  };
  auto ldB = [&](int b, int fc, int ks) -> bf16x8 {
    int byte = (((((wc & 1) << 6) + (fc << 4) + c16)) << 7) + (ks << 6) + (g << 4);
    return *(const bf16x8*)(ldsB + b * 32768 + (wc >> 1) * 16384 + (byte ^ xm));
  };

  f32x4 acc[8][4] = {};

  // ---- prologue: tile0 {A-lo,A-hi,B-lo,B-hi}, tile1 {B-lo,B-hi} = 12 loads ----
  stage(X,  m0,       0,  ldsA);                    // t0 A-lo
  stage(X,  m0 + 128, 0,  ldsA + 16384);            // t0 A-hi
  stage(WT, n0,       0,  ldsB);                    // t0 B-lo
  stage(WT, n0 + 128, 0,  ldsB + 16384);            // t0 B-hi
  stage(WT, n0,       64, ldsB + 32768);            // t1 B-lo
  stage(WT, n0 + 128, 64, ldsB + 32768 + 16384);    // t1 B-hi
  FENCE; asm volatile("s_waitcnt vmcnt(4)" ::: "memory");   // tile0's 8 loads done
  __builtin_amdgcn_s_barrier();
  __builtin_amdgcn_sched_barrier(0); FENCE;

  for (int t = 0; t < NT; ++t) {
    const int b = t & 1;
    const int bn = b ^ 1;                         // (t+1)&1
    const int u1 = (t + 1 < NT) ? t + 1 : NT - 1; // clamped -> uniform vmcnt counts
    const int u2 = (t + 2 < NT) ? t + 2 : NT - 1;
    bf16x8 af[4][2], b01[2][2], b23[2][2];

    // ---------- P1 ----------
#pragma unroll
    for (int fr = 0; fr < 4; ++fr)
#pragma unroll
      for (int ks = 0; ks < 2; ++ks) af[fr][ks] = ldA(b, fr, ks);
#pragma unroll
    for (int fc = 0; fc < 2; ++fc)
#pragma unroll
      for (int ks = 0; ks < 2; ++ks) b01[fc][ks] = ldB(b, fc, ks);
    stage(X, m0, u1 * 64, ldsA + bn * 32768);                   // A-lo(t+1)
    SYNC_MID6;
    __builtin_amdgcn_s_setprio(1);
#pragma unroll
    for (int fr = 0; fr < 4; ++fr)
#pragma unroll
      for (int fc = 0; fc < 2; ++fc)
#pragma unroll
        for (int ks = 0; ks < 2; ++ks)
          acc[fr][fc] = __builtin_amdgcn_mfma_f32_16x16x32_bf16(af[fr][ks], b01[fc][ks], acc[fr][fc], 0, 0, 0);
    __builtin_amdgcn_s_setprio(0);
    SYNC_END;

    // ---------- P2 ----------
#pragma unroll
    for (int fc = 0; fc < 2; ++fc)
#pragma unroll
      for (int ks = 0; ks < 2; ++ks) b23[fc][ks] = ldB(b, fc + 2, ks);
    stage(X, m0 + 128, u1 * 64, ldsA + bn * 32768 + 16384);     // A-hi(t+1)
    SYNC_MID6;
    __builtin_amdgcn_s_setprio(1);
#pragma unroll
    for (int fr = 0; fr < 4; ++fr)
#pragma unroll
      for (int fc = 0; fc < 2; ++fc)
#pragma unroll
        for (int ks = 0; ks < 2; ++ks)
          acc[fr][fc + 2] = __builtin_amdgcn_mfma_f32_16x16x32_bf16(af[fr][ks], b23[fc][ks], acc[fr][fc + 2], 0, 0, 0);
    __builtin_amdgcn_s_setprio(0);
    SYNC_END;

    // ---------- P3 ----------
#pragma unroll
    for (int fr = 0; fr < 4; ++fr)
#pragma unroll
      for (int ks = 0; ks < 2; ++ks) af[fr][ks] = ldA(b, fr + 4, ks);
    stage(WT, n0, u2 * 64, ldsB + b * 32768);                   // B-lo(t+2)
    SYNC_MID6;
    __builtin_amdgcn_s_setprio(1);
#pragma unroll
    for (int fr = 0; fr < 4; ++fr)
#pragma unroll
      for (int fc = 0; fc < 2; ++fc)
#pragma unroll
        for (int ks = 0; ks < 2; ++ks)
          acc[fr + 4][fc + 2] = __builtin_amdgcn_mfma_f32_16x16x32_bf16(af[fr][ks], b23[fc][ks], acc[fr + 4][fc + 2], 0, 0, 0);
    __builtin_amdgcn_s_setprio(0);
    SYNC_END;

    // ---------- P4 ----------
    stage(WT, n0 + 128, u2 * 64, ldsB + b * 32768 + 16384);     // B-hi(t+2)
    SYNC_MID6;
    __builtin_amdgcn_s_setprio(1);
#pragma unroll
    for (int fr = 0; fr < 4; ++fr)
#pragma unroll
      for (int fc = 0; fc < 2; ++fc)
#pragma unroll
        for (int ks = 0; ks < 2; ++ks)
          acc[fr + 4][fc] = __builtin_amdgcn_mfma_f32_16x16x32_bf16(af[fr][ks], b01[fc][ks], acc[fr + 4][fc], 0, 0, 0);
    __builtin_amdgcn_s_setprio(0);
    SYNC_END;
  }

  // ---- epilogue: bias + relu + bf16 store (D: col=lane&15, row=4*(lane>>4)+r) ----
#pragma unroll
  for (int fr = 0; fr < 8; ++fr)
#pragma unroll
    for (int fc = 0; fc < 4; ++fc) {
      int col = n0 + wc * 64 + fc * 16 + c16;
      float bias = b1[col];
#pragma unroll
      for (int r = 0; r < 4; ++r) {
        int row = m0 + wr * 128 + fr * 16 + g * 4 + r;
        float v = acc[fr][fc][r] + bias;
        Hb[(size_t)row * HDIM + col] = __float2bfloat16(v > 0.f ? v : 0.f);
      }
    }
}

// ---------- K4: router w = softmax(h @ W2 + b2), one wave per row ----------
__global__ __launch_bounds__(256) void k_router(const __hip_bfloat16* __restrict__ Hb,
                                                const float* __restrict__ W2,
                                                const float* __restrict__ b2,
                                                float* __restrict__ wout) {
  const int wave = threadIdx.x >> 6, lane = threadIdx.x & 63;
  const int n = blockIdx.x * 4 + wave;
  float acc[8] = {0, 0, 0, 0, 0, 0, 0, 0};
  for (int it = 0; it < HDIM / 512; ++it) {
    int h0 = it * 512 + lane * 8;
    bf16x8 xv = *(const bf16x8*)&Hb[(size_t)n * HDIM + h0];
#pragma unroll
    for (int j = 0; j < 8; ++j) {
      float xf = (float)xv[j];
      const float4* wr = (const float4*)&W2[(size_t)(h0 + j) * EXP];
      float4 wa = wr[0], wb = wr[1];
      acc[0] += xf * wa.x; acc[1] += xf * wa.y; acc[2] += xf * wa.z; acc[3] += xf * wa.w;
      acc[4] += xf * wb.x; acc[5] += xf * wb.y; acc[6] += xf * wb.z; acc[7] += xf * wb.w;
    }
  }
#pragma unroll
  for (int off = 32; off; off >>= 1)
#pragma unroll
    for (int e = 0; e < 8; ++e) acc[e] += __shfl_xor(acc[e], off, 64);
  float lg[8], m = -1e30f;
#pragma unroll
  for (int e = 0; e < 8; ++e) { lg[e] = acc[e] + b2[e]; m = fmaxf(m, lg[e]); }
  float s = 0.f;
#pragma unroll
  for (int e = 0; e < 8; ++e) { lg[e] = __expf(lg[e] - m); s += lg[e]; }
  float inv = 1.f / s;
  if (lane < 8) wout[(size_t)n * EXP + lane] = lg[lane] * inv;
}

// ---------- K5: t partials = x @ AT^T, bf16 MFMA, 128x64 tile, K split x4 ----------
__global__ __launch_bounds__(256) void k_gemm_t(const __hip_bfloat16* __restrict__ X,
                                                const __hip_bfloat16* __restrict__ AT,
                                                float* __restrict__ tp) {
  __shared__ __hip_bfloat16 As[128][32];
  __shared__ __hip_bfloat16 Bs[64][32];
  const int tid = threadIdx.x;
  const int wave = tid >> 6, lane = tid & 63;
  const int g = lane >> 4, c16 = lane & 15;
  const int m0 = blockIdx.x * 128;
  const int kc = blockIdx.y;                 // K chunk of 512
  const int wm = (wave >> 1) * 64, wn = (wave & 1) * 32;
  f32x4 acc[4][2] = {};
  const int scol = (lane & 3) * 8;
  const __hip_bfloat16* ga = X  + (size_t)(m0 + wave * 32 + (lane >> 2)) * HDIM + scol;
  const __hip_bfloat16* gb = AT + (size_t)(wave * 16 + (lane >> 2)) * HDIM + scol;
  for (int k0 = kc * 512; k0 < kc * 512 + 512; k0 += 32) {
    __syncthreads();
    gload_lds16(ga + k0,             &As[wave * 32][0]);
    gload_lds16(ga + k0 + 16 * HDIM, &As[wave * 32 + 16][0]);
    gload_lds16(gb + k0,             &Bs[wave * 16][0]);
    __syncthreads();
    bf16x8 af[4], bfr[2];
#pragma unroll
    for (int i = 0; i < 4; ++i) af[i]  = *(const bf16x8*)&As[wm + i * 16 + c16][g * 8];
#pragma unroll
    for (int j = 0; j < 2; ++j) bfr[j] = *(const bf16x8*)&Bs[wn + j * 16 + c16][g * 8];
#pragma unroll
    for (int i = 0; i < 4; ++i)
#pragma unroll
      for (int j = 0; j < 2; ++j)
        acc[i][j] = __builtin_amdgcn_mfma_f32_16x16x32_bf16(af[i], bfr[j], acc[i][j], 0, 0, 0);
  }
#pragma unroll
  for (int i = 0; i < 4; ++i)
#pragma unroll
    for (int j = 0; j < 2; ++j)
#pragma unroll
      for (int r = 0; r < 4; ++r) {
        int row = m0 + wm + i * 16 + g * 4 + r;
        int col = wn + j * 16 + c16;
        tp[((size_t)kc * NROWS + row) * 64 + col] = acc[i][j][r];
      }
}

// ---------- K5b: c[n][er] = (sum_kc tp) * w[n][er>>3], written IN PLACE over
// tp chunk 0 (each thread reads exactly the elements it overwrites -> race-free)
__global__ __launch_bounds__(256) void k_combine(float* __restrict__ tp,
                                                 const float* __restrict__ wgt) {
  size_t i = ((size_t)blockIdx.x * 256 + threadIdx.x) * 4;
  const size_t CH = (size_t)NROWS * 64;
  f32x4 s = *(const f32x4*)(tp + i);
  s += *(const f32x4*)(tp + i + CH);
  s += *(const f32x4*)(tp + i + 2 * CH);
  s += *(const f32x4*)(tp + i + 3 * CH);
  size_t n = i >> 6;
  int er = (int)(i & 63);                 // multiple of 4 -> same expert for all 4
  float w = wgt[n * EXP + (er >> 3)];
  *(f32x4*)(tp + i) = s * w;
}

// ---------- K6: out[n][h] = sum_er c[n][er] * B[er][h], fp32 VALU ----------
// 32 rows x 256 cols per block -> 2048 blocks = 8 blocks/CU
__global__ __launch_bounds__(256) void k_final(const float* __restrict__ c,
                                               const float* __restrict__ Bm,
                                               float* __restrict__ out) {
  __shared__ float cs[32][64];
  const int t = threadIdx.x;
  const int n0 = (blockIdx.x >> 3) * 32;
  const int col0 = (blockIdx.x & 7) * 256;
  {
    int idx = t * 8;                      // 2048 floats = 256 threads x 8
    const float* src = c + (size_t)n0 * 64 + idx;
    *(f32x4*)&cs[idx >> 6][idx & 63] = *(const f32x4*)src;
    *(f32x4*)&cs[(idx + 4) >> 6][(idx + 4) & 63] = *(const f32x4*)(src + 4);
  }
  __syncthreads();
  const int rg = t >> 5;                  // 8 groups of 4 rows
  const int cg = t & 31;                  // 32 groups of 8 cols
  const int cc = col0 + cg * 8;
  f32x4 acc0[4] = {}, acc1[4] = {};
#pragma unroll 4
  for (int er = 0; er < 64; ++er) {
    f32x4 b0  = *(const f32x4*)&Bm[(size_t)er * HDIM + cc];
    f32x4 b1v = *(const f32x4*)&Bm[(size_t)er * HDIM + cc + 4];
#pragma unroll
    for (int r = 0; r < 4; ++r) {
      float cv = cs[rg * 4 + r][er];      // wave-uniform per 32-lane half -> broadcast
      acc0[r] += cv * b0;
      acc1[r] += cv * b1v;
    }
  }
#pragma unroll
  for (int r = 0; r < 4; ++r) {
    size_t o = (size_t)(n0 + rg * 4 + r) * HDIM + cc;
    *(f32x4*)&out[o] = acc0[r];
    *(f32x4*)&out[o + 4] = acc1[r];
  }
}

extern "C" void kernel_launch(void* const* d_in, const int* in_sizes, int n_in,
                              void* d_out, int out_size, void* d_ws, size_t ws_size,
                              hipStream_t stream) {
  const float* x  = (const float*)d_in[0];
  const float* W1 = (const float*)d_in[1];
  const float* b1 = (const float*)d_in[2];
  const float* W2 = (const float*)d_in[3];
  const float* b2 = (const float*)d_in[4];
  const float* A  = (const float*)d_in[5];
  const float* B  = (const float*)d_in[6];
  float* out = (float*)d_out;

  char* ws = (char*)d_ws;
  __hip_bfloat16* xb  = (__hip_bfloat16*)(ws);
  __hip_bfloat16* w1t = (__hip_bfloat16*)(ws + 33554432);
  __hip_bfloat16* hb  = (__hip_bfloat16*)(ws + 41943040);
  __hip_bfloat16* at  = (__hip_bfloat16*)(ws + 75497472);
  float* wgt          = (float*)(ws + 75759616);
  float* tp           = (float*)(ws + 76021760);
  if (ws_size < 84410368) return;  // insufficient scratch -> fail loudly

  hipFuncSetAttribute((const void*)k_gemm_h8,
                      hipFuncAttributeMaxDynamicSharedMemorySize, 131072);

  k_cast_bf16<<<NROWS * HDIM / (256 * 8), 256, 0, stream>>>(x, xb);
  k_transcast<<<dim3(HDIM / 64, HDIM / 64), 256, 0, stream>>>(W1, w1t);
  k_cast_A<<<EXP * 8, 256, 0, stream>>>(A, at);
  k_gemm_h8<<<dim3(HDIM / 256, NROWS / 256), 512, 131072, stream>>>(xb, w1t, b1, hb);
  k_router<<<NROWS / 4, 256, 0, stream>>>(hb, W2, b2, wgt);
  k_gemm_t<<<dim3(NROWS / 128, 4), 256, 0, stream>>>(xb, at, tp);
  k_combine<<<NROWS * 64 / (256 * 4), 256, 0, stream>>>(tp, wgt);
  k_final<<<2048, 256, 0, stream>>>(tp /*=c*/, B, out);
}

// Round 4
// 218.126 us; speedup vs baseline: 1.3235x; 1.0150x over previous
//
#include <hip/hip_runtime.h>
#include <hip/hip_bf16.h>

// Problem constants (fixed by reference)
#define NROWS 8192
#define HDIM  2048
#define EXP   8
#define RANK  8

typedef float  f32x4  __attribute__((ext_vector_type(4)));
typedef __bf16 bf16x8 __attribute__((ext_vector_type(8)));

// async global->LDS, 16B per lane; LDS dest must be wave-uniform (HW: base + lane*16)
__device__ __forceinline__ void gload_lds16(const void* g, void* l) {
  __builtin_amdgcn_global_load_lds((const __attribute__((address_space(1))) void*)g,
                                   (__attribute__((address_space(3))) void*)l, 16, 0, 0);
}

#define FENCE asm volatile("" ::: "memory")
// mid-phase sync: staged data (issued >=4 phases ago) is now visible to all waves
#define SYNC_MID6 do { FENCE; asm volatile("s_waitcnt vmcnt(6)" ::: "memory"); \
  __builtin_amdgcn_s_barrier(); __builtin_amdgcn_sched_barrier(0); FENCE; } while (0)
// end-phase sync: all waves' LDS reads of this phase are done (reads precede own MFMA
// via compiler lgkmcnt; MFMA precedes this barrier)
#define SYNC_END do { FENCE; __builtin_amdgcn_sched_barrier(0); \
  __builtin_amdgcn_s_barrier(); __builtin_amdgcn_sched_barrier(0); FENCE; } while (0)

// ---------- K1: elementwise f32 -> bf16 cast (x) ----------
__global__ __launch_bounds__(256) void k_cast_bf16(const float* __restrict__ src,
                                                   __hip_bfloat16* __restrict__ dst) {
  size_t i = ((size_t)blockIdx.x * 256 + threadIdx.x) * 8;
  float4 a = *(const float4*)(src + i);
  float4 b = *(const float4*)(src + i + 4);
  union { __hip_bfloat16 h[8]; int4 v; } u;
  u.h[0] = __float2bfloat16(a.x); u.h[1] = __float2bfloat16(a.y);
  u.h[2] = __float2bfloat16(a.z); u.h[3] = __float2bfloat16(a.w);
  u.h[4] = __float2bfloat16(b.x); u.h[5] = __float2bfloat16(b.y);
  u.h[6] = __float2bfloat16(b.z); u.h[7] = __float2bfloat16(b.w);
  *(int4*)(dst + i) = u.v;
}

// ---------- K2: W1 [k][n] f32 -> W1T [n][k] bf16 (LDS-tiled transpose) ----------
__global__ __launch_bounds__(256) void k_transcast(const float* __restrict__ W,
                                                   __hip_bfloat16* __restrict__ WT) {
  __shared__ float s[64][65];
  int n0 = blockIdx.x * 64, k0 = blockIdx.y * 64;
  for (int i = 0; i < 16; ++i) {
    int idx = threadIdx.x + i * 256;
    int r = idx >> 6, c = idx & 63;
    s[r][c] = W[(size_t)(k0 + r) * HDIM + n0 + c];
  }
  __syncthreads();
  for (int i = 0; i < 16; ++i) {
    int idx = threadIdx.x + i * 256;
    int r = idx >> 6, c = idx & 63;
    WT[(size_t)(n0 + r) * HDIM + k0 + c] = __float2bfloat16(s[c][r]);
  }
}

// ---------- K2b: A [E][H][R] f32 -> AT [E*R][H] bf16 ----------
__global__ __launch_bounds__(256) void k_cast_A(const float* __restrict__ A,
                                                __hip_bfloat16* __restrict__ AT) {
  __shared__ float s[2048];                      // 256 h x 8 r
  int e = blockIdx.x >> 3, ht = blockIdx.x & 7;
  const float* src = A + (size_t)e * (HDIM * RANK) + (size_t)ht * 256 * RANK;
  for (int i = 0; i < 8; ++i) s[threadIdx.x + i * 256] = src[threadIdx.x + i * 256];
  __syncthreads();
  for (int i = 0; i < 8; ++i) {
    int idx = threadIdx.x + i * 256;
    int r = idx >> 8, hh = idx & 255;
    AT[(size_t)(e * RANK + r) * HDIM + ht * 256 + hh] = __float2bfloat16(s[hh * 8 + r]);
  }
}

// ---------- K3: h = relu(x @ W1 + b1) -- 256x256 8-phase MFMA template ----------
// 8 waves (2M x 4N), BK=64, 128KB LDS (2 dbuf x 2 half x 128 x 64 x bf16 x {A,B}),
// 3-bit row-XOR swizzle: phys_chunk = logical_chunk ^ (row&7)  (chunk = 16B unit).
// Rows are 128B = exactly 32 banks, so a b128 quarter-wave (16 lanes, same chunk,
// 16 rows) is 16-way bank-aliased unswizzled; 3-bit XOR spreads it to 2 lanes/bank
// (= free, m136). gload_lds dest stays LINEAR; the global SOURCE chunk is
// pre-permuted (both-sides-or-neither). Permutation stays inside each 128B row ->
// global coalescing unchanged.
// Counted vmcnt(6) per phase (3 half-tiles in flight), setprio around MFMA.
// Phase/stage schedule (tile t, buf b=t&1):
//   P1: read A fr0-3 + B fc0-1 (12 ds_read) | stage A-lo(t+1) | MFMA q(r0-3,c0-1)
//   P2: read B fc2-3 (4)                    | stage A-hi(t+1) | MFMA q(r0-3,c2-3)
//   P3: read A fr4-7 (8)                    | stage B-lo(t+2) | MFMA q(r4-7,c2-3)
//   P4: (no reads, B kept in regs)          | stage B-hi(t+2) | MFMA q(r4-7,c0-1)
// Region-free proof: B(t) LDS free after P2 (staged P3/P4), A(t) free after P3
// (staged next tile's P1/P2). Every stage->consume gap >= 4 phases => vmcnt(6) valid.
__global__ __launch_bounds__(512, 2) void k_gemm_h8(const __hip_bfloat16* __restrict__ X,
                                                    const __hip_bfloat16* __restrict__ WT,
                                                    const float* __restrict__ b1,
                                                    __hip_bfloat16* __restrict__ Hb) {
  extern __shared__ char lds[];
  char* ldsA = lds;                 // [2 buf][2 half][128 rows][64 k] bf16 = 64KB
  char* ldsB = lds + 65536;         // same, rows = N-cols (WT is [n][k])
  const int tid = threadIdx.x;
  const int wid = tid >> 6, lane = tid & 63;
  const int wr = wid >> 2, wc = wid & 3;        // 2 x 4 wave grid
  const int g = lane >> 4, c16 = lane & 15;
  const int xm = (c16 & 7) << 4;                // read-side swizzle XOR (3 row bits -> chunk bits)
  const int m0 = blockIdx.y * 256, n0 = blockIdx.x * 256;
  const int NT = HDIM / 64;                     // 32 K-tiles

  // stage-source geometry (inverse swizzle: logical chunk = phys chunk ^ (row&7))
  int srow[2], scol[2];
#pragma unroll
  for (int q = 0; q < 2; ++q) {
    int L = (q * 512 + tid) * 16;               // linear phys byte within 16KB half
    int row = L >> 7;
    int chunkp = (L >> 4) & 7;
    srow[q] = row;
    scol[q] = (chunkp ^ (row & 7)) << 3;        // bf16 elements (chunk*8)
  }
  auto stage = [&](const __hip_bfloat16* gb, int rowBase, int kBase, char* half) {
    gload_lds16(gb + (size_t)(rowBase + srow[0]) * HDIM + kBase + scol[0], half + tid * 16);
    gload_lds16(gb + (size_t)(rowBase + srow[1]) * HDIM + kBase + scol[1], half + 8192 + tid * 16);
  };
  auto ldA = [&](int b, int fr, int ks) -> bf16x8 {
    int byte = (((fr << 4) + c16) << 7) + (ks << 6) + (g << 4);
    return *(const bf16x8*)(ldsA + b * 32768 + wr * 16384 + (byte ^ xm));
  };
  auto ldB = [&](int b, int fc, int ks) -> bf16x8 {
    int byte = (((((wc & 1) << 6) + (fc << 4) + c16)) << 7) + (ks << 6) + (g << 4);
    return *(const bf16x8*)(ldsB + b * 32768 + (wc >> 1) * 16384 + (byte ^ xm));
  };

  f32x4 acc[8][4] = {};

  // ---- prologue: tile0 {A-lo,A-hi,B-lo,B-hi}, tile1 {B-lo,B-hi} = 12 loads ----
  stage(X,  m0,       0,  ldsA);                    // t0 A-lo
  stage(X,  m0 + 128, 0,  ldsA + 16384);            // t0 A-hi
  stage(WT, n0,       0,  ldsB);                    // t0 B-lo
  stage(WT, n0 + 128, 0,  ldsB + 16384);            // t0 B-hi
  stage(WT, n0,       64, ldsB + 32768);            // t1 B-lo
  stage(WT, n0 + 128, 64, ldsB + 32768 + 16384);    // t1 B-hi
  FENCE; asm volatile("s_waitcnt vmcnt(4)" ::: "memory");   // tile0's 8 loads done
  __builtin_amdgcn_s_barrier();
  __builtin_amdgcn_sched_barrier(0); FENCE;

  for (int t = 0; t < NT; ++t) {
    const int b = t & 1;
    const int bn = b ^ 1;                         // (t+1)&1
    const int u1 = (t + 1 < NT) ? t + 1 : NT - 1; // clamped -> uniform vmcnt counts
    const int u2 = (t + 2 < NT) ? t + 2 : NT - 1;
    bf16x8 af[4][2], b01[2][2], b23[2][2];

    // ---------- P1 ----------
#pragma unroll
    for (int fr = 0; fr < 4; ++fr)
#pragma unroll
      for (int ks = 0; ks < 2; ++ks) af[fr][ks] = ldA(b, fr, ks);
#pragma unroll
    for (int fc = 0; fc < 2; ++fc)
#pragma unroll
      for (int ks = 0; ks < 2; ++ks) b01[fc][ks] = ldB(b, fc, ks);
    stage(X, m0, u1 * 64, ldsA + bn * 32768);                   // A-lo(t+1)
    SYNC_MID6;
    __builtin_amdgcn_s_setprio(1);
#pragma unroll
    for (int fr = 0; fr < 4; ++fr)
#pragma unroll
      for (int fc = 0; fc < 2; ++fc)
#pragma unroll
        for (int ks = 0; ks < 2; ++ks)
          acc[fr][fc] = __builtin_amdgcn_mfma_f32_16x16x32_bf16(af[fr][ks], b01[fc][ks], acc[fr][fc], 0, 0, 0);
    __builtin_amdgcn_s_setprio(0);
    SYNC_END;

    // ---------- P2 ----------
#pragma unroll
    for (int fc = 0; fc < 2; ++fc)
#pragma unroll
      for (int ks = 0; ks < 2; ++ks) b23[fc][ks] = ldB(b, fc + 2, ks);
    stage(X, m0 + 128, u1 * 64, ldsA + bn * 32768 + 16384);     // A-hi(t+1)
    SYNC_MID6;
    __builtin_amdgcn_s_setprio(1);
#pragma unroll
    for (int fr = 0; fr < 4; ++fr)
#pragma unroll
      for (int fc = 0; fc < 2; ++fc)
#pragma unroll
        for (int ks = 0; ks < 2; ++ks)
          acc[fr][fc + 2] = __builtin_amdgcn_mfma_f32_16x16x32_bf16(af[fr][ks], b23[fc][ks], acc[fr][fc + 2], 0, 0, 0);
    __builtin_amdgcn_s_setprio(0);
    SYNC_END;

    // ---------- P3 ----------
#pragma unroll
    for (int fr = 0; fr < 4; ++fr)
#pragma unroll
      for (int ks = 0; ks < 2; ++ks) af[fr][ks] = ldA(b, fr + 4, ks);
    stage(WT, n0, u2 * 64, ldsB + b * 32768);                   // B-lo(t+2)
    SYNC_MID6;
    __builtin_amdgcn_s_setprio(1);
#pragma unroll
    for (int fr = 0; fr < 4; ++fr)
#pragma unroll
      for (int fc = 0; fc < 2; ++fc)
#pragma unroll
        for (int ks = 0; ks < 2; ++ks)
          acc[fr + 4][fc + 2] = __builtin_amdgcn_mfma_f32_16x16x32_bf16(af[fr][ks], b23[fc][ks], acc[fr + 4][fc + 2], 0, 0, 0);
    __builtin_amdgcn_s_setprio(0);
    SYNC_END;

    // ---------- P4 ----------
    stage(WT, n0 + 128, u2 * 64, ldsB + b * 32768 + 16384);     // B-hi(t+2)
    SYNC_MID6;
    __builtin_amdgcn_s_setprio(1);
#pragma unroll
    for (int fr = 0; fr < 4; ++fr)
#pragma unroll
      for (int fc = 0; fc < 2; ++fc)
#pragma unroll
        for (int ks = 0; ks < 2; ++ks)
          acc[fr + 4][fc] = __builtin_amdgcn_mfma_f32_16x16x32_bf16(af[fr][ks], b01[fc][ks], acc[fr + 4][fc], 0, 0, 0);
    __builtin_amdgcn_s_setprio(0);
    SYNC_END;
  }

  // ---- epilogue: bias + relu + bf16 store (D: col=lane&15, row=4*(lane>>4)+r) ----
#pragma unroll
  for (int fr = 0; fr < 8; ++fr)
#pragma unroll
    for (int fc = 0; fc < 4; ++fc) {
      int col = n0 + wc * 64 + fc * 16 + c16;
      float bias = b1[col];
#pragma unroll
      for (int r = 0; r < 4; ++r) {
        int row = m0 + wr * 128 + fr * 16 + g * 4 + r;
        float v = acc[fr][fc][r] + bias;
        Hb[(size_t)row * HDIM + col] = __float2bfloat16(v > 0.f ? v : 0.f);
      }
    }
}

// ---------- K4: router w = softmax(h @ W2 + b2), one wave per row ----------
__global__ __launch_bounds__(256) void k_router(const __hip_bfloat16* __restrict__ Hb,
                                                const float* __restrict__ W2,
                                                const float* __restrict__ b2,
                                                float* __restrict__ wout) {
  const int wave = threadIdx.x >> 6, lane = threadIdx.x & 63;
  const int n = blockIdx.x * 4 + wave;
  float acc[8] = {0, 0, 0, 0, 0, 0, 0, 0};
  for (int it = 0; it < HDIM / 512; ++it) {
    int h0 = it * 512 + lane * 8;
    bf16x8 xv = *(const bf16x8*)&Hb[(size_t)n * HDIM + h0];
#pragma unroll
    for (int j = 0; j < 8; ++j) {
      float xf = (float)xv[j];
      const float4* wr = (const float4*)&W2[(size_t)(h0 + j) * EXP];
      float4 wa = wr[0], wb = wr[1];
      acc[0] += xf * wa.x; acc[1] += xf * wa.y; acc[2] += xf * wa.z; acc[3] += xf * wa.w;
      acc[4] += xf * wb.x; acc[5] += xf * wb.y; acc[6] += xf * wb.z; acc[7] += xf * wb.w;
    }
  }
#pragma unroll
  for (int off = 32; off; off >>= 1)
#pragma unroll
    for (int e = 0; e < 8; ++e) acc[e] += __shfl_xor(acc[e], off, 64);
  float lg[8], m = -1e30f;
#pragma unroll
  for (int e = 0; e < 8; ++e) { lg[e] = acc[e] + b2[e]; m = fmaxf(m, lg[e]); }
  float s = 0.f;
#pragma unroll
  for (int e = 0; e < 8; ++e) { lg[e] = __expf(lg[e] - m); s += lg[e]; }
  float inv = 1.f / s;
  if (lane < 8) wout[(size_t)n * EXP + lane] = lg[lane] * inv;
}

// ---------- K5: t partials = x @ AT^T, bf16 MFMA, 128x64 tile, K split x4 ----------
__global__ __launch_bounds__(256) void k_gemm_t(const __hip_bfloat16* __restrict__ X,
                                                const __hip_bfloat16* __restrict__ AT,
                                                float* __restrict__ tp) {
  __shared__ __hip_bfloat16 As[128][32];
  __shared__ __hip_bfloat16 Bs[64][32];
  const int tid = threadIdx.x;
  const int wave = tid >> 6, lane = tid & 63;
  const int g = lane >> 4, c16 = lane & 15;
  const int m0 = blockIdx.x * 128;
  const int kc = blockIdx.y;                 // K chunk of 512
  const int wm = (wave >> 1) * 64, wn = (wave & 1) * 32;
  f32x4 acc[4][2] = {};
  const int scol = (lane & 3) * 8;
  const __hip_bfloat16* ga = X  + (size_t)(m0 + wave * 32 + (lane >> 2)) * HDIM + scol;
  const __hip_bfloat16* gb = AT + (size_t)(wave * 16 + (lane >> 2)) * HDIM + scol;
  for (int k0 = kc * 512; k0 < kc * 512 + 512; k0 += 32) {
    __syncthreads();
    gload_lds16(ga + k0,             &As[wave * 32][0]);
    gload_lds16(ga + k0 + 16 * HDIM, &As[wave * 32 + 16][0]);
    gload_lds16(gb + k0,             &Bs[wave * 16][0]);
    __syncthreads();
    bf16x8 af[4], bfr[2];
#pragma unroll
    for (int i = 0; i < 4; ++i) af[i]  = *(const bf16x8*)&As[wm + i * 16 + c16][g * 8];
#pragma unroll
    for (int j = 0; j < 2; ++j) bfr[j] = *(const bf16x8*)&Bs[wn + j * 16 + c16][g * 8];
#pragma unroll
    for (int i = 0; i < 4; ++i)
#pragma unroll
      for (int j = 0; j < 2; ++j)
        acc[i][j] = __builtin_amdgcn_mfma_f32_16x16x32_bf16(af[i], bfr[j], acc[i][j], 0, 0, 0);
  }
#pragma unroll
  for (int i = 0; i < 4; ++i)
#pragma unroll
    for (int j = 0; j < 2; ++j)
#pragma unroll
      for (int r = 0; r < 4; ++r) {
        int row = m0 + wm + i * 16 + g * 4 + r;
        int col = wn + j * 16 + c16;
        tp[((size_t)kc * NROWS + row) * 64 + col] = acc[i][j][r];
      }
}

// ---------- K5b: c[n][er] = (sum_kc tp) * w[n][er>>3], written IN PLACE over
// tp chunk 0 (each thread reads exactly the elements it overwrites -> race-free)
__global__ __launch_bounds__(256) void k_combine(float* __restrict__ tp,
                                                 const float* __restrict__ wgt) {
  size_t i = ((size_t)blockIdx.x * 256 + threadIdx.x) * 4;
  const size_t CH = (size_t)NROWS * 64;
  f32x4 s = *(const f32x4*)(tp + i);
  s += *(const f32x4*)(tp + i + CH);
  s += *(const f32x4*)(tp + i + 2 * CH);
  s += *(const f32x4*)(tp + i + 3 * CH);
  size_t n = i >> 6;
  int er = (int)(i & 63);                 // multiple of 4 -> same expert for all 4
  float w = wgt[n * EXP + (er >> 3)];
  *(f32x4*)(tp + i) = s * w;
}

// ---------- K6: out[n][h] = sum_er c[n][er] * B[er][h], fp32 VALU ----------
// 32 rows x 256 cols per block -> 2048 blocks = 8 blocks/CU
__global__ __launch_bounds__(256) void k_final(const float* __restrict__ c,
                                               const float* __restrict__ Bm,
                                               float* __restrict__ out) {
  __shared__ float cs[32][64];
  const int t = threadIdx.x;
  const int n0 = (blockIdx.x >> 3) * 32;
  const int col0 = (blockIdx.x & 7) * 256;
  {
    int idx = t * 8;                      // 2048 floats = 256 threads x 8
    const float* src = c + (size_t)n0 * 64 + idx;
    *(f32x4*)&cs[idx >> 6][idx & 63] = *(const f32x4*)src;
    *(f32x4*)&cs[(idx + 4) >> 6][(idx + 4) & 63] = *(const f32x4*)(src + 4);
  }
  __syncthreads();
  const int rg = t >> 5;                  // 8 groups of 4 rows
  const int cg = t & 31;                  // 32 groups of 8 cols
  const int cc = col0 + cg * 8;
  f32x4 acc0[4] = {}, acc1[4] = {};
#pragma unroll 4
  for (int er = 0; er < 64; ++er) {
    f32x4 b0  = *(const f32x4*)&Bm[(size_t)er * HDIM + cc];
    f32x4 b1v = *(const f32x4*)&Bm[(size_t)er * HDIM + cc + 4];
#pragma unroll
    for (int r = 0; r < 4; ++r) {
      float cv = cs[rg * 4 + r][er];      // wave-uniform per 32-lane half -> broadcast
      acc0[r] += cv * b0;
      acc1[r] += cv * b1v;
    }
  }
#pragma unroll
  for (int r = 0; r < 4; ++r) {
    size_t o = (size_t)(n0 + rg * 4 + r) * HDIM + cc;
    *(f32x4*)&out[o] = acc0[r];
    *(f32x4*)&out[o + 4] = acc1[r];
  }
}

extern "C" void kernel_launch(void* const* d_in, const int* in_sizes, int n_in,
                              void* d_out, int out_size, void* d_ws, size_t ws_size,
                              hipStream_t stream) {
  const float* x  = (const float*)d_in[0];
  const float* W1 = (const float*)d_in[1];
  const float* b1 = (const float*)d_in[2];
  const float* W2 = (const float*)d_in[3];
  const float* b2 = (const float*)d_in[4];
  const float* A  = (const float*)d_in[5];
  const float* B  = (const float*)d_in[6];
  float* out = (float*)d_out;

  char* ws = (char*)d_ws;
  __hip_bfloat16* xb  = (__hip_bfloat16*)(ws);
  __hip_bfloat16* w1t = (__hip_bfloat16*)(ws + 33554432);
  __hip_bfloat16* hb  = (__hip_bfloat16*)(ws + 41943040);
  __hip_bfloat16* at  = (__hip_bfloat16*)(ws + 75497472);
  float* wgt          = (float*)(ws + 75759616);
  float* tp           = (float*)(ws + 76021760);
  if (ws_size < 84410368) return;  // insufficient scratch -> fail loudly

  hipFuncSetAttribute((const void*)k_gemm_h8,
                      hipFuncAttributeMaxDynamicSharedMemorySize, 131072);

  k_cast_bf16<<<NROWS * HDIM / (256 * 8), 256, 0, stream>>>(x, xb);
  k_transcast<<<dim3(HDIM / 64, HDIM / 64), 256, 0, stream>>>(W1, w1t);
  k_cast_A<<<EXP * 8, 256, 0, stream>>>(A, at);
  k_gemm_h8<<<dim3(HDIM / 256, NROWS / 256), 512, 131072, stream>>>(xb, w1t, b1, hb);
  k_router<<<NROWS / 4, 256, 0, stream>>>(hb, W2, b2, wgt);
  k_gemm_t<<<dim3(NROWS / 128, 4), 256, 0, stream>>>(xb, at, tp);
  k_combine<<<NROWS * 64 / (256 * 4), 256, 0, stream>>>(tp, wgt);
  k_final<<<2048, 256, 0, stream>>>(tp /*=c*/, B, out);
}

// Round 5
// 168.752 us; speedup vs baseline: 1.7108x; 1.2926x over previous
//
#include <hip/hip_runtime.h>
#include <hip/hip_bf16.h>

// Problem constants (fixed by reference)
#define NROWS 8192
#define HDIM  2048
#define EXP   8
#define RANK  8

typedef float  f32x4  __attribute__((ext_vector_type(4)));
typedef __bf16 bf16x8 __attribute__((ext_vector_type(8)));

// async global->LDS, 16B per lane; LDS dest must be wave-uniform (HW: base + lane*16)
__device__ __forceinline__ void gload_lds16(const void* g, void* l) {
  __builtin_amdgcn_global_load_lds((const __attribute__((address_space(1))) void*)g,
                                   (__attribute__((address_space(3))) void*)l, 16, 0, 0);
}

#define FENCE asm volatile("" ::: "memory")
// mid-phase sync: staged data (issued >=4 phases ago) is now visible to all waves
#define SYNC_MID6 do { FENCE; asm volatile("s_waitcnt vmcnt(6)" ::: "memory"); \
  __builtin_amdgcn_s_barrier(); __builtin_amdgcn_sched_barrier(0); FENCE; } while (0)
// end-phase sync: all waves' LDS reads of this phase are done
#define SYNC_END do { FENCE; __builtin_amdgcn_sched_barrier(0); \
  __builtin_amdgcn_s_barrier(); __builtin_amdgcn_sched_barrier(0); FENCE; } while (0)

// ---------- K1: elementwise f32 -> bf16 cast (x) ----------
__global__ __launch_bounds__(256) void k_cast_bf16(const float* __restrict__ src,
                                                   __hip_bfloat16* __restrict__ dst) {
  size_t i = ((size_t)blockIdx.x * 256 + threadIdx.x) * 8;
  float4 a = *(const float4*)(src + i);
  float4 b = *(const float4*)(src + i + 4);
  union { __hip_bfloat16 h[8]; int4 v; } u;
  u.h[0] = __float2bfloat16(a.x); u.h[1] = __float2bfloat16(a.y);
  u.h[2] = __float2bfloat16(a.z); u.h[3] = __float2bfloat16(a.w);
  u.h[4] = __float2bfloat16(b.x); u.h[5] = __float2bfloat16(b.y);
  u.h[6] = __float2bfloat16(b.z); u.h[7] = __float2bfloat16(b.w);
  *(int4*)(dst + i) = u.v;
}

// ---------- K2: W1 [k][n] f32 -> W1T [n][k] bf16 (LDS-tiled transpose) ----------
__global__ __launch_bounds__(256) void k_transcast(const float* __restrict__ W,
                                                   __hip_bfloat16* __restrict__ WT) {
  __shared__ float s[64][65];
  int n0 = blockIdx.x * 64, k0 = blockIdx.y * 64;
  for (int i = 0; i < 16; ++i) {
    int idx = threadIdx.x + i * 256;
    int r = idx >> 6, c = idx & 63;
    s[r][c] = W[(size_t)(k0 + r) * HDIM + n0 + c];
  }
  __syncthreads();
  for (int i = 0; i < 16; ++i) {
    int idx = threadIdx.x + i * 256;
    int r = idx >> 6, c = idx & 63;
    WT[(size_t)(n0 + r) * HDIM + k0 + c] = __float2bfloat16(s[c][r]);
  }
}

// ---------- K2b: A [E][H][R] f32 -> AT [E*R][H] bf16 ----------
__global__ __launch_bounds__(256) void k_cast_A(const float* __restrict__ A,
                                                __hip_bfloat16* __restrict__ AT) {
  __shared__ float s[2048];                      // 256 h x 8 r
  int e = blockIdx.x >> 3, ht = blockIdx.x & 7;
  const float* src = A + (size_t)e * (HDIM * RANK) + (size_t)ht * 256 * RANK;
  for (int i = 0; i < 8; ++i) s[threadIdx.x + i * 256] = src[threadIdx.x + i * 256];
  __syncthreads();
  for (int i = 0; i < 8; ++i) {
    int idx = threadIdx.x + i * 256;
    int r = idx >> 8, hh = idx & 255;
    AT[(size_t)(e * RANK + r) * HDIM + ht * 256 + hh] = __float2bfloat16(s[hh * 8 + r]);
  }
}

// ---------- K3: h = relu(x @ W1 + b1) + FUSED router logit partials ----------
// 256x256 8-phase MFMA, 8 waves (2M x 4N), BK=64, 128KB LDS, 3-bit row-XOR swizzle
// (bank-conflict-free, verified R3: SQ_LDS_BANK_CONFLICT = 0), counted vmcnt(6),
// setprio around MFMA. NEW vs R3:
//  (a) bijective XCD swizzle: each XCD owns 4 row-panels x all 8 col-blocks ->
//      A-panels XCD-local (4MB, L2-resident) instead of every XCD streaming all of xb.
//  (b) epilogue computes this block's partial router logits
//      plog[colblk][n][e] = sum_{cols in block} relu(h) * W2[col][e]  (f32, no Hb store).
//      Reduction: fc in regs -> 16-lane shfl tree -> LDS cross-wave (wc) reduce.
//      Deterministic (no atomics; each (colblk,rowblk) writes a distinct slice).
__global__ __launch_bounds__(512, 2) void k_gemm_h8(const __hip_bfloat16* __restrict__ X,
                                                    const __hip_bfloat16* __restrict__ WT,
                                                    const float* __restrict__ b1,
                                                    const float* __restrict__ W2,
                                                    float* __restrict__ plog) {
  extern __shared__ char lds[];
  char* ldsA = lds;                 // [2 buf][2 half][128 rows][64 k] bf16 = 64KB
  char* ldsB = lds + 65536;
  const int tid = threadIdx.x;
  const int wid = tid >> 6, lane = tid & 63;
  const int wr = wid >> 2, wc = wid & 3;        // 2 x 4 wave grid
  const int g = lane >> 4, c16 = lane & 15;
  const int xm = (c16 & 7) << 4;                // read-side swizzle XOR (3 row bits -> chunk bits)
  // bijective XCD swizzle: dispatch linear id round-robins XCDs (id%8);
  // remap so XCD k gets rowblks 4k..4k+3 x all colblks (A working set 4MB ~ L2)
  const int lin = blockIdx.y * 8 + blockIdx.x;  // gridDim.x == 8
  const int nid = (lin & 7) * 32 + (lin >> 3);
  const int cb = nid & 7, rb = nid >> 3;
  const int m0 = rb * 256, n0 = cb * 256;
  const int NT = HDIM / 64;                     // 32 K-tiles

  // stage-source geometry (inverse swizzle: logical chunk = phys chunk ^ (row&7))
  int srow[2], scol[2];
#pragma unroll
  for (int q = 0; q < 2; ++q) {
    int L = (q * 512 + tid) * 16;               // linear phys byte within 16KB half
    int row = L >> 7;
    int chunkp = (L >> 4) & 7;
    srow[q] = row;
    scol[q] = (chunkp ^ (row & 7)) << 3;        // bf16 elements (chunk*8)
  }
  auto stage = [&](const __hip_bfloat16* gb, int rowBase, int kBase, char* half) {
    gload_lds16(gb + (size_t)(rowBase + srow[0]) * HDIM + kBase + scol[0], half + tid * 16);
    gload_lds16(gb + (size_t)(rowBase + srow[1]) * HDIM + kBase + scol[1], half + 8192 + tid * 16);
  };
  auto ldA = [&](int b, int fr, int ks) -> bf16x8 {
    int byte = (((fr << 4) + c16) << 7) + (ks << 6) + (g << 4);
    return *(const bf16x8*)(ldsA + b * 32768 + wr * 16384 + (byte ^ xm));
  };
  auto ldB = [&](int b, int fc, int ks) -> bf16x8 {
    int byte = (((((wc & 1) << 6) + (fc << 4) + c16)) << 7) + (ks << 6) + (g << 4);
    return *(const bf16x8*)(ldsB + b * 32768 + (wc >> 1) * 16384 + (byte ^ xm));
  };

  f32x4 acc[8][4] = {};

  // ---- prologue: tile0 {A-lo,A-hi,B-lo,B-hi}, tile1 {B-lo,B-hi} = 12 loads ----
  stage(X,  m0,       0,  ldsA);
  stage(X,  m0 + 128, 0,  ldsA + 16384);
  stage(WT, n0,       0,  ldsB);
  stage(WT, n0 + 128, 0,  ldsB + 16384);
  stage(WT, n0,       64, ldsB + 32768);
  stage(WT, n0 + 128, 64, ldsB + 32768 + 16384);
  FENCE; asm volatile("s_waitcnt vmcnt(4)" ::: "memory");
  __builtin_amdgcn_s_barrier();
  __builtin_amdgcn_sched_barrier(0); FENCE;

  for (int t = 0; t < NT; ++t) {
    const int b = t & 1;
    const int bn = b ^ 1;
    const int u1 = (t + 1 < NT) ? t + 1 : NT - 1; // clamped -> uniform vmcnt counts
    const int u2 = (t + 2 < NT) ? t + 2 : NT - 1;
    bf16x8 af[4][2], b01[2][2], b23[2][2];

    // ---------- P1 ----------
#pragma unroll
    for (int fr = 0; fr < 4; ++fr)
#pragma unroll
      for (int ks = 0; ks < 2; ++ks) af[fr][ks] = ldA(b, fr, ks);
#pragma unroll
    for (int fc = 0; fc < 2; ++fc)
#pragma unroll
      for (int ks = 0; ks < 2; ++ks) b01[fc][ks] = ldB(b, fc, ks);
    stage(X, m0, u1 * 64, ldsA + bn * 32768);                   // A-lo(t+1)
    SYNC_MID6;
    __builtin_amdgcn_s_setprio(1);
#pragma unroll
    for (int fr = 0; fr < 4; ++fr)
#pragma unroll
      for (int fc = 0; fc < 2; ++fc)
#pragma unroll
        for (int ks = 0; ks < 2; ++ks)
          acc[fr][fc] = __builtin_amdgcn_mfma_f32_16x16x32_bf16(af[fr][ks], b01[fc][ks], acc[fr][fc], 0, 0, 0);
    __builtin_amdgcn_s_setprio(0);
    SYNC_END;

    // ---------- P2 ----------
#pragma unroll
    for (int fc = 0; fc < 2; ++fc)
#pragma unroll
      for (int ks = 0; ks < 2; ++ks) b23[fc][ks] = ldB(b, fc + 2, ks);
    stage(X, m0 + 128, u1 * 64, ldsA + bn * 32768 + 16384);     // A-hi(t+1)
    SYNC_MID6;
    __builtin_amdgcn_s_setprio(1);
#pragma unroll
    for (int fr = 0; fr < 4; ++fr)
#pragma unroll
      for (int fc = 0; fc < 2; ++fc)
#pragma unroll
        for (int ks = 0; ks < 2; ++ks)
          acc[fr][fc + 2] = __builtin_amdgcn_mfma_f32_16x16x32_bf16(af[fr][ks], b23[fc][ks], acc[fr][fc + 2], 0, 0, 0);
    __builtin_amdgcn_s_setprio(0);
    SYNC_END;

    // ---------- P3 ----------
#pragma unroll
    for (int fr = 0; fr < 4; ++fr)
#pragma unroll
      for (int ks = 0; ks < 2; ++ks) af[fr][ks] = ldA(b, fr + 4, ks);
    stage(WT, n0, u2 * 64, ldsB + b * 32768);                   // B-lo(t+2)
    SYNC_MID6;
    __builtin_amdgcn_s_setprio(1);
#pragma unroll
    for (int fr = 0; fr < 4; ++fr)
#pragma unroll
      for (int fc = 0; fc < 2; ++fc)
#pragma unroll
        for (int ks = 0; ks < 2; ++ks)
          acc[fr + 4][fc + 2] = __builtin_amdgcn_mfma_f32_16x16x32_bf16(af[fr][ks], b23[fc][ks], acc[fr + 4][fc + 2], 0, 0, 0);
    __builtin_amdgcn_s_setprio(0);
    SYNC_END;

    // ---------- P4 ----------
    stage(WT, n0 + 128, u2 * 64, ldsB + b * 32768 + 16384);     // B-hi(t+2)
    SYNC_MID6;
    __builtin_amdgcn_s_setprio(1);
#pragma unroll
    for (int fr = 0; fr < 4; ++fr)
#pragma unroll
      for (int fc = 0; fc < 2; ++fc)
#pragma unroll
        for (int ks = 0; ks < 2; ++ks)
          acc[fr + 4][fc] = __builtin_amdgcn_mfma_f32_16x16x32_bf16(af[fr][ks], b01[fc][ks], acc[fr + 4][fc], 0, 0, 0);
    __builtin_amdgcn_s_setprio(0);
    SYNC_END;
  }

  // ---- fused epilogue: router logit partials (no Hb store) ----
  // drain in-flight clamped-tail stages before reusing LDS
  FENCE; asm volatile("s_waitcnt vmcnt(0)" ::: "memory");
  __builtin_amdgcn_s_barrier(); FENCE;
  float* pl = (float*)lds;                       // [4 wc][256 rows][8 e] = 32KB

  f32x4 w2lo[4], w2hi[4];
  float bias[4];
#pragma unroll
  for (int fc = 0; fc < 4; ++fc) {
    int col = n0 + wc * 64 + fc * 16 + c16;
    const float* wp = W2 + (size_t)col * EXP;
    w2lo[fc] = *(const f32x4*)wp;
    w2hi[fc] = *(const f32x4*)(wp + 4);
    bias[fc] = b1[col];
  }
#pragma unroll
  for (int fr = 0; fr < 8; ++fr)
#pragma unroll
    for (int r = 0; r < 4; ++r) {
      f32x4 p0 = {}, p1 = {};
#pragma unroll
      for (int fc = 0; fc < 4; ++fc) {
        float v = acc[fr][fc][r] + bias[fc];
        v = v > 0.f ? v : 0.f;                   // f32 h (better than bf16 round-trip)
        p0 += v * w2lo[fc];
        p1 += v * w2hi[fc];
      }
      // reduce over the 16 c16-lanes (same row within group g; xor<16 stays in group)
#pragma unroll
      for (int off = 8; off; off >>= 1)
#pragma unroll
        for (int q = 0; q < 4; ++q) {
          p0[q] += __shfl_xor(p0[q], off, 64);
          p1[q] += __shfl_xor(p1[q], off, 64);
        }
      if (c16 == 0) {
        int rl = wr * 128 + fr * 16 + g * 4 + r;
        *(f32x4*)&pl[((wc << 8) + rl) * 8]     = p0;
        *(f32x4*)&pl[((wc << 8) + rl) * 8 + 4] = p1;
      }
    }
  __syncthreads();
  {
    int idx = tid * 4;                           // 0..2047: 256 rows x 8 experts
    f32x4 s = *(const f32x4*)&pl[idx];
    s += *(const f32x4*)&pl[2048 + idx];
    s += *(const f32x4*)&pl[4096 + idx];
    s += *(const f32x4*)&pl[6144 + idx];
    *(f32x4*)&plog[((size_t)cb * NROWS + m0) * 8 + idx] = s;
  }
}

// ---------- K4: logits = sum_cb plog + b2 -> softmax -> wgt ----------
__global__ __launch_bounds__(256) void k_softmax(const float* __restrict__ plog,
                                                 const float* __restrict__ b2,
                                                 float* __restrict__ wgt) {
  int n = blockIdx.x * 256 + threadIdx.x;
  f32x4 lo = *(const f32x4*)b2, hi = *(const f32x4*)(b2 + 4);
#pragma unroll
  for (int cbk = 0; cbk < 8; ++cbk) {
    const float* p = plog + ((size_t)cbk * NROWS + n) * 8;
    lo += *(const f32x4*)p;
    hi += *(const f32x4*)(p + 4);
  }
  float m = lo[0];
#pragma unroll
  for (int q = 1; q < 4; ++q) m = fmaxf(m, lo[q]);
#pragma unroll
  for (int q = 0; q < 4; ++q) m = fmaxf(m, hi[q]);
  float s = 0.f;
#pragma unroll
  for (int q = 0; q < 4; ++q) { lo[q] = __expf(lo[q] - m); s += lo[q]; }
#pragma unroll
  for (int q = 0; q < 4; ++q) { hi[q] = __expf(hi[q] - m); s += hi[q]; }
  float inv = 1.f / s;
  *(f32x4*)&wgt[(size_t)n * 8]     = lo * inv;
  *(f32x4*)&wgt[(size_t)n * 8 + 4] = hi * inv;
}

// ---------- K5: t partials = x @ AT^T, bf16 MFMA, 128x64 tile, K split x4 ----------
__global__ __launch_bounds__(256) void k_gemm_t(const __hip_bfloat16* __restrict__ X,
                                                const __hip_bfloat16* __restrict__ AT,
                                                float* __restrict__ tp) {
  __shared__ __hip_bfloat16 As[128][32];
  __shared__ __hip_bfloat16 Bs[64][32];
  const int tid = threadIdx.x;
  const int wave = tid >> 6, lane = tid & 63;
  const int g = lane >> 4, c16 = lane & 15;
  const int m0 = blockIdx.x * 128;
  const int kc = blockIdx.y;                 // K chunk of 512
  const int wm = (wave >> 1) * 64, wn = (wave & 1) * 32;
  f32x4 acc[4][2] = {};
  const int scol = (lane & 3) * 8;
  const __hip_bfloat16* ga = X  + (size_t)(m0 + wave * 32 + (lane >> 2)) * HDIM + scol;
  const __hip_bfloat16* gb = AT + (size_t)(wave * 16 + (lane >> 2)) * HDIM + scol;
  for (int k0 = kc * 512; k0 < kc * 512 + 512; k0 += 32) {
    __syncthreads();
    gload_lds16(ga + k0,             &As[wave * 32][0]);
    gload_lds16(ga + k0 + 16 * HDIM, &As[wave * 32 + 16][0]);
    gload_lds16(gb + k0,             &Bs[wave * 16][0]);
    __syncthreads();
    bf16x8 af[4], bfr[2];
#pragma unroll
    for (int i = 0; i < 4; ++i) af[i]  = *(const bf16x8*)&As[wm + i * 16 + c16][g * 8];
#pragma unroll
    for (int j = 0; j < 2; ++j) bfr[j] = *(const bf16x8*)&Bs[wn + j * 16 + c16][g * 8];
#pragma unroll
    for (int i = 0; i < 4; ++i)
#pragma unroll
      for (int j = 0; j < 2; ++j)
        acc[i][j] = __builtin_amdgcn_mfma_f32_16x16x32_bf16(af[i], bfr[j], acc[i][j], 0, 0, 0);
  }
#pragma unroll
  for (int i = 0; i < 4; ++i)
#pragma unroll
    for (int j = 0; j < 2; ++j)
#pragma unroll
      for (int r = 0; r < 4; ++r) {
        int row = m0 + wm + i * 16 + g * 4 + r;
        int col = wn + j * 16 + c16;
        tp[((size_t)kc * NROWS + row) * 64 + col] = acc[i][j][r];
      }
}

// ---------- K5b: c[n][er] = (sum_kc tp) * w[n][er>>3], in place over tp chunk 0 ----------
__global__ __launch_bounds__(256) void k_combine(float* __restrict__ tp,
                                                 const float* __restrict__ wgt) {
  size_t i = ((size_t)blockIdx.x * 256 + threadIdx.x) * 4;
  const size_t CH = (size_t)NROWS * 64;
  f32x4 s = *(const f32x4*)(tp + i);
  s += *(const f32x4*)(tp + i + CH);
  s += *(const f32x4*)(tp + i + 2 * CH);
  s += *(const f32x4*)(tp + i + 3 * CH);
  size_t n = i >> 6;
  int er = (int)(i & 63);
  float w = wgt[n * EXP + (er >> 3)];
  *(f32x4*)(tp + i) = s * w;
}

// ---------- K6: out[n][h] = sum_er c[n][er] * B[er][h], fp32 VALU ----------
__global__ __launch_bounds__(256) void k_final(const float* __restrict__ c,
                                               const float* __restrict__ Bm,
                                               float* __restrict__ out) {
  __shared__ float cs[32][64];
  const int t = threadIdx.x;
  const int n0 = (blockIdx.x >> 3) * 32;
  const int col0 = (blockIdx.x & 7) * 256;
  {
    int idx = t * 8;
    const float* src = c + (size_t)n0 * 64 + idx;
    *(f32x4*)&cs[idx >> 6][idx & 63] = *(const f32x4*)src;
    *(f32x4*)&cs[(idx + 4) >> 6][(idx + 4) & 63] = *(const f32x4*)(src + 4);
  }
  __syncthreads();
  const int rg = t >> 5;
  const int cg = t & 31;
  const int cc = col0 + cg * 8;
  f32x4 acc0[4] = {}, acc1[4] = {};
#pragma unroll 4
  for (int er = 0; er < 64; ++er) {
    f32x4 b0  = *(const f32x4*)&Bm[(size_t)er * HDIM + cc];
    f32x4 b1v = *(const f32x4*)&Bm[(size_t)er * HDIM + cc + 4];
#pragma unroll
    for (int r = 0; r < 4; ++r) {
      float cv = cs[rg * 4 + r][er];
      acc0[r] += cv * b0;
      acc1[r] += cv * b1v;
    }
  }
#pragma unroll
  for (int r = 0; r < 4; ++r) {
    size_t o = (size_t)(n0 + rg * 4 + r) * HDIM + cc;
    *(f32x4*)&out[o] = acc0[r];
    *(f32x4*)&out[o + 4] = acc1[r];
  }
}

extern "C" void kernel_launch(void* const* d_in, const int* in_sizes, int n_in,
                              void* d_out, int out_size, void* d_ws, size_t ws_size,
                              hipStream_t stream) {
  const float* x  = (const float*)d_in[0];
  const float* W1 = (const float*)d_in[1];
  const float* b1 = (const float*)d_in[2];
  const float* W2 = (const float*)d_in[3];
  const float* b2 = (const float*)d_in[4];
  const float* A  = (const float*)d_in[5];
  const float* B  = (const float*)d_in[6];
  float* out = (float*)d_out;

  char* ws = (char*)d_ws;
  // ws layout (bytes):
  //   xb   [8192*2048] bf16 : 33,554,432
  //   w1t  [2048*2048] bf16 :  8,388,608
  //   plog [8*8192*8]  f32  :  2,097,152   (in old hb region)
  //   at   [64*2048]   bf16 :    262,144
  //   wgt  [8192*8]    f32  :    262,144
  //   tp   [4*8192*64] f32  :  8,388,608
  __hip_bfloat16* xb  = (__hip_bfloat16*)(ws);
  __hip_bfloat16* w1t = (__hip_bfloat16*)(ws + 33554432);
  float* plog         = (float*)(ws + 41943040);
  __hip_bfloat16* at  = (__hip_bfloat16*)(ws + 75497472);
  float* wgt          = (float*)(ws + 75759616);
  float* tp           = (float*)(ws + 76021760);
  if (ws_size < 84410368) return;  // insufficient scratch -> fail loudly

  hipFuncSetAttribute((const void*)k_gemm_h8,
                      hipFuncAttributeMaxDynamicSharedMemorySize, 131072);

  k_cast_bf16<<<NROWS * HDIM / (256 * 8), 256, 0, stream>>>(x, xb);
  k_transcast<<<dim3(HDIM / 64, HDIM / 64), 256, 0, stream>>>(W1, w1t);
  k_cast_A<<<EXP * 8, 256, 0, stream>>>(A, at);
  k_gemm_h8<<<dim3(HDIM / 256, NROWS / 256), 512, 131072, stream>>>(xb, w1t, b1, W2, plog);
  k_softmax<<<NROWS / 256, 256, 0, stream>>>(plog, b2, wgt);
  k_gemm_t<<<dim3(NROWS / 128, 4), 256, 0, stream>>>(xb, at, tp);
  k_combine<<<NROWS * 64 / (256 * 4), 256, 0, stream>>>(tp, wgt);
  k_final<<<2048, 256, 0, stream>>>(tp /*=c*/, B, out);
}

// Round 6
// 156.272 us; speedup vs baseline: 1.8474x; 1.0799x over previous
//
#include <hip/hip_runtime.h>
#include <hip/hip_bf16.h>

// Problem constants (fixed by reference)
#define NROWS 8192
#define HDIM  2048
#define EXP   8
#define RANK  8

typedef float  f32x4  __attribute__((ext_vector_type(4)));
typedef __bf16 bf16x8 __attribute__((ext_vector_type(8)));

// async global->LDS, 16B per lane; LDS dest must be wave-uniform (HW: base + lane*16)
__device__ __forceinline__ void gload_lds16(const void* g, void* l) {
  __builtin_amdgcn_global_load_lds((const __attribute__((address_space(1))) void*)g,
                                   (__attribute__((address_space(3))) void*)l, 16, 0, 0);
}

#define FENCE asm volatile("" ::: "memory")
// mid-phase sync: staged data (issued >=4 phases ago) is now visible to all waves
#define SYNC_MID6 do { FENCE; asm volatile("s_waitcnt vmcnt(6)" ::: "memory"); \
  __builtin_amdgcn_s_barrier(); __builtin_amdgcn_sched_barrier(0); FENCE; } while (0)
// end-phase sync: all waves' LDS reads of this phase are done
#define SYNC_END do { FENCE; __builtin_amdgcn_sched_barrier(0); \
  __builtin_amdgcn_s_barrier(); __builtin_amdgcn_sched_barrier(0); FENCE; } while (0)

// ---------- K1: elementwise f32 -> bf16 cast (x) ----------
__global__ __launch_bounds__(256) void k_cast_bf16(const float* __restrict__ src,
                                                   __hip_bfloat16* __restrict__ dst) {
  size_t i = ((size_t)blockIdx.x * 256 + threadIdx.x) * 8;
  float4 a = *(const float4*)(src + i);
  float4 b = *(const float4*)(src + i + 4);
  union { __hip_bfloat16 h[8]; int4 v; } u;
  u.h[0] = __float2bfloat16(a.x); u.h[1] = __float2bfloat16(a.y);
  u.h[2] = __float2bfloat16(a.z); u.h[3] = __float2bfloat16(a.w);
  u.h[4] = __float2bfloat16(b.x); u.h[5] = __float2bfloat16(b.y);
  u.h[6] = __float2bfloat16(b.z); u.h[7] = __float2bfloat16(b.w);
  *(int4*)(dst + i) = u.v;
}

// ---------- K2: W1 [k][n] f32 -> W1T [n][k] bf16 (LDS-tiled transpose) ----------
__global__ __launch_bounds__(256) void k_transcast(const float* __restrict__ W,
                                                   __hip_bfloat16* __restrict__ WT) {
  __shared__ float s[64][65];
  int n0 = blockIdx.x * 64, k0 = blockIdx.y * 64;
  for (int i = 0; i < 16; ++i) {
    int idx = threadIdx.x + i * 256;
    int r = idx >> 6, c = idx & 63;
    s[r][c] = W[(size_t)(k0 + r) * HDIM + n0 + c];
  }
  __syncthreads();
  for (int i = 0; i < 16; ++i) {
    int idx = threadIdx.x + i * 256;
    int r = idx >> 6, c = idx & 63;
    WT[(size_t)(n0 + r) * HDIM + k0 + c] = __float2bfloat16(s[c][r]);
  }
}

// ---------- K2b: A [E][H][R] f32 -> AT [E*R][H] bf16 ----------
__global__ __launch_bounds__(256) void k_cast_A(const float* __restrict__ A,
                                                __hip_bfloat16* __restrict__ AT) {
  __shared__ float s[2048];                      // 256 h x 8 r
  int e = blockIdx.x >> 3, ht = blockIdx.x & 7;
  const float* src = A + (size_t)e * (HDIM * RANK) + (size_t)ht * 256 * RANK;
  for (int i = 0; i < 8; ++i) s[threadIdx.x + i * 256] = src[threadIdx.x + i * 256];
  __syncthreads();
  for (int i = 0; i < 8; ++i) {
    int idx = threadIdx.x + i * 256;
    int r = idx >> 8, hh = idx & 255;
    AT[(size_t)(e * RANK + r) * HDIM + ht * 256 + hh] = __float2bfloat16(s[hh * 8 + r]);
  }
}

// ---------- K3: h = relu(x @ W1 + b1) + FUSED router logit partials ----------
// 256x256 8-phase MFMA, 8 waves (2M x 4N), BK=64, 128KB LDS, 3-bit row-XOR swizzle
// (bank-conflict-free, verified R3/R4: SQ_LDS_BANK_CONFLICT = 0), counted vmcnt(6),
// setprio, bijective XCD swizzle (R4: FETCH 135->50MB).
// Epilogue v2 (R5 fix): the shfl-tree reduce (1024 ds_swizzle/lane ~= 20us/CU on the
// one LDS pipe) is replaced by an LDS transpose-reduce: per fr-chunk each lane writes
// its fc-reduced 8 expert partials to red[wc][c16][rloc][e] (c16 stride 289 words,
// rloc stride 9 -> bank spread), then 512 threads re-read along (wc,c16) and sum.
// Deterministic (no atomics; fixed summation order).
__global__ __launch_bounds__(512, 2) void k_gemm_h8(const __hip_bfloat16* __restrict__ X,
                                                    const __hip_bfloat16* __restrict__ WT,
                                                    const float* __restrict__ b1,
                                                    const float* __restrict__ W2,
                                                    float* __restrict__ plog) {
  extern __shared__ char lds[];
  char* ldsA = lds;                 // [2 buf][2 half][128 rows][64 k] bf16 = 64KB
  char* ldsB = lds + 65536;
  const int tid = threadIdx.x;
  const int wid = tid >> 6, lane = tid & 63;
  const int wr = wid >> 2, wc = wid & 3;        // 2 x 4 wave grid
  const int g = lane >> 4, c16 = lane & 15;
  const int xm = (c16 & 7) << 4;                // read-side swizzle XOR (3 row bits -> chunk bits)
  // bijective XCD swizzle: dispatch linear id round-robins XCDs (id%8);
  // remap so XCD k gets rowblks 4k..4k+3 x all colblks (A working set 4MB ~ L2)
  const int lin = blockIdx.y * 8 + blockIdx.x;  // gridDim.x == 8
  const int nid = (lin & 7) * 32 + (lin >> 3);
  const int cb = nid & 7, rb = nid >> 3;
  const int m0 = rb * 256, n0 = cb * 256;
  const int NT = HDIM / 64;                     // 32 K-tiles

  // stage-source geometry (inverse swizzle: logical chunk = phys chunk ^ (row&7))
  int srow[2], scol[2];
#pragma unroll
  for (int q = 0; q < 2; ++q) {
    int L = (q * 512 + tid) * 16;               // linear phys byte within 16KB half
    int row = L >> 7;
    int chunkp = (L >> 4) & 7;
    srow[q] = row;
    scol[q] = (chunkp ^ (row & 7)) << 3;        // bf16 elements (chunk*8)
  }
  auto stage = [&](const __hip_bfloat16* gb, int rowBase, int kBase, char* half) {
    gload_lds16(gb + (size_t)(rowBase + srow[0]) * HDIM + kBase + scol[0], half + tid * 16);
    gload_lds16(gb + (size_t)(rowBase + srow[1]) * HDIM + kBase + scol[1], half + 8192 + tid * 16);
  };
  auto ldA = [&](int b, int fr, int ks) -> bf16x8 {
    int byte = (((fr << 4) + c16) << 7) + (ks << 6) + (g << 4);
    return *(const bf16x8*)(ldsA + b * 32768 + wr * 16384 + (byte ^ xm));
  };
  auto ldB = [&](int b, int fc, int ks) -> bf16x8 {
    int byte = (((((wc & 1) << 6) + (fc << 4) + c16)) << 7) + (ks << 6) + (g << 4);
    return *(const bf16x8*)(ldsB + b * 32768 + (wc >> 1) * 16384 + (byte ^ xm));
  };

  f32x4 acc[8][4] = {};

  // ---- prologue: tile0 {A-lo,A-hi,B-lo,B-hi}, tile1 {B-lo,B-hi} = 12 loads ----
  stage(X,  m0,       0,  ldsA);
  stage(X,  m0 + 128, 0,  ldsA + 16384);
  stage(WT, n0,       0,  ldsB);
  stage(WT, n0 + 128, 0,  ldsB + 16384);
  stage(WT, n0,       64, ldsB + 32768);
  stage(WT, n0 + 128, 64, ldsB + 32768 + 16384);
  FENCE; asm volatile("s_waitcnt vmcnt(4)" ::: "memory");
  __builtin_amdgcn_s_barrier();
  __builtin_amdgcn_sched_barrier(0); FENCE;

  for (int t = 0; t < NT; ++t) {
    const int b = t & 1;
    const int bn = b ^ 1;
    const int u1 = (t + 1 < NT) ? t + 1 : NT - 1; // clamped -> uniform vmcnt counts
    const int u2 = (t + 2 < NT) ? t + 2 : NT - 1;
    bf16x8 af[4][2], b01[2][2], b23[2][2];

    // ---------- P1 ----------
#pragma unroll
    for (int fr = 0; fr < 4; ++fr)
#pragma unroll
      for (int ks = 0; ks < 2; ++ks) af[fr][ks] = ldA(b, fr, ks);
#pragma unroll
    for (int fc = 0; fc < 2; ++fc)
#pragma unroll
      for (int ks = 0; ks < 2; ++ks) b01[fc][ks] = ldB(b, fc, ks);
    stage(X, m0, u1 * 64, ldsA + bn * 32768);                   // A-lo(t+1)
    SYNC_MID6;
    __builtin_amdgcn_s_setprio(1);
#pragma unroll
    for (int fr = 0; fr < 4; ++fr)
#pragma unroll
      for (int fc = 0; fc < 2; ++fc)
#pragma unroll
        for (int ks = 0; ks < 2; ++ks)
          acc[fr][fc] = __builtin_amdgcn_mfma_f32_16x16x32_bf16(af[fr][ks], b01[fc][ks], acc[fr][fc], 0, 0, 0);
    __builtin_amdgcn_s_setprio(0);
    SYNC_END;

    // ---------- P2 ----------
#pragma unroll
    for (int fc = 0; fc < 2; ++fc)
#pragma unroll
      for (int ks = 0; ks < 2; ++ks) b23[fc][ks] = ldB(b, fc + 2, ks);
    stage(X, m0 + 128, u1 * 64, ldsA + bn * 32768 + 16384);     // A-hi(t+1)
    SYNC_MID6;
    __builtin_amdgcn_s_setprio(1);
#pragma unroll
    for (int fr = 0; fr < 4; ++fr)
#pragma unroll
      for (int fc = 0; fc < 2; ++fc)
#pragma unroll
        for (int ks = 0; ks < 2; ++ks)
          acc[fr][fc + 2] = __builtin_amdgcn_mfma_f32_16x16x32_bf16(af[fr][ks], b23[fc][ks], acc[fr][fc + 2], 0, 0, 0);
    __builtin_amdgcn_s_setprio(0);
    SYNC_END;

    // ---------- P3 ----------
#pragma unroll
    for (int fr = 0; fr < 4; ++fr)
#pragma unroll
      for (int ks = 0; ks < 2; ++ks) af[fr][ks] = ldA(b, fr + 4, ks);
    stage(WT, n0, u2 * 64, ldsB + b * 32768);                   // B-lo(t+2)
    SYNC_MID6;
    __builtin_amdgcn_s_setprio(1);
#pragma unroll
    for (int fr = 0; fr < 4; ++fr)
#pragma unroll
      for (int fc = 0; fc < 2; ++fc)
#pragma unroll
        for (int ks = 0; ks < 2; ++ks)
          acc[fr + 4][fc + 2] = __builtin_amdgcn_mfma_f32_16x16x32_bf16(af[fr][ks], b23[fc][ks], acc[fr + 4][fc + 2], 0, 0, 0);
    __builtin_amdgcn_s_setprio(0);
    SYNC_END;

    // ---------- P4 ----------
    stage(WT, n0 + 128, u2 * 64, ldsB + b * 32768 + 16384);     // B-hi(t+2)
    SYNC_MID6;
    __builtin_amdgcn_s_setprio(1);
#pragma unroll
    for (int fr = 0; fr < 4; ++fr)
#pragma unroll
      for (int fc = 0; fc < 2; ++fc)
#pragma unroll
        for (int ks = 0; ks < 2; ++ks)
          acc[fr + 4][fc] = __builtin_amdgcn_mfma_f32_16x16x32_bf16(af[fr][ks], b01[fc][ks], acc[fr + 4][fc], 0, 0, 0);
    __builtin_amdgcn_s_setprio(0);
    SYNC_END;
  }

  // ---- fused epilogue v2: router logit partials via LDS transpose-reduce ----
  // drain in-flight clamped-tail stages before reusing LDS
  FENCE; asm volatile("s_waitcnt vmcnt(0)" ::: "memory");
  __builtin_amdgcn_s_barrier(); FENCE;
  // red[wc 4][c16 16][rloc 32][e 8] f32; c16 stride 289 words, rloc stride 9 words
  // -> bank = (c16 + 9*rloc + e) % 32: full c16 spread, g contributes 4g. <=4-way.
  float* red = (float*)lds;                      // 63*289+286 = 18493 words = 74KB

  f32x4 w2lo[4], w2hi[4];
  float bias[4];
#pragma unroll
  for (int fc = 0; fc < 4; ++fc) {
    int col = n0 + wc * 64 + fc * 16 + c16;
    const float* wp = W2 + (size_t)col * EXP;
    w2lo[fc] = *(const f32x4*)wp;
    w2hi[fc] = *(const f32x4*)(wp + 4);
    bias[fc] = b1[col];
  }
  const int oidx = tid >> 1, prt = tid & 1;
  const int rrl = oidx >> 3, re = oidx & 7;      // reader's (rloc, e)
  for (int fr = 0; fr < 8; ++fr) {
#pragma unroll
    for (int r = 0; r < 4; ++r) {
      f32x4 p0 = {}, p1 = {};
#pragma unroll
      for (int fc = 0; fc < 4; ++fc) {
        float v = acc[fr][fc][r] + bias[fc];
        v = v > 0.f ? v : 0.f;                   // f32 h (no bf16 round-trip)
        p0 += v * w2lo[fc];
        p1 += v * w2hi[fc];
      }
      int base = (wc * 16 + c16) * 289 + (wr * 16 + g * 4 + r) * 9;
#pragma unroll
      for (int e = 0; e < 4; ++e) { red[base + e] = p0[e]; red[base + 4 + e] = p1[e]; }
    }
    __syncthreads();
    {
      float s = 0.f;
#pragma unroll
      for (int wq = 0; wq < 4; ++wq)
#pragma unroll
        for (int i = 0; i < 8; ++i)
          s += red[(wq * 16 + prt * 8 + i) * 289 + rrl * 9 + re];
      s += __shfl_xor(s, 1, 64);                 // combine prt halves (adjacent lanes)
      if (prt == 0) {
        int grow = (rrl >> 4) * 128 + fr * 16 + (rrl & 15);
        plog[((size_t)cb * NROWS + m0 + grow) * 8 + re] = s;
      }
    }
    __syncthreads();                             // reads done before next fr overwrites
  }
}

// ---------- K4: logits = sum_cb plog + b2 -> softmax -> wgt ----------
__global__ __launch_bounds__(256) void k_softmax(const float* __restrict__ plog,
                                                 const float* __restrict__ b2,
                                                 float* __restrict__ wgt) {
  int n = blockIdx.x * 256 + threadIdx.x;
  f32x4 lo = *(const f32x4*)b2, hi = *(const f32x4*)(b2 + 4);
#pragma unroll
  for (int cbk = 0; cbk < 8; ++cbk) {
    const float* p = plog + ((size_t)cbk * NROWS + n) * 8;
    lo += *(const f32x4*)p;
    hi += *(const f32x4*)(p + 4);
  }
  float m = lo[0];
#pragma unroll
  for (int q = 1; q < 4; ++q) m = fmaxf(m, lo[q]);
#pragma unroll
  for (int q = 0; q < 4; ++q) m = fmaxf(m, hi[q]);
  float s = 0.f;
#pragma unroll
  for (int q = 0; q < 4; ++q) { lo[q] = __expf(lo[q] - m); s += lo[q]; }
#pragma unroll
  for (int q = 0; q < 4; ++q) { hi[q] = __expf(hi[q] - m); s += hi[q]; }
  float inv = 1.f / s;
  *(f32x4*)&wgt[(size_t)n * 8]     = lo * inv;
  *(f32x4*)&wgt[(size_t)n * 8 + 4] = hi * inv;
}

// ---------- K5: t partials = x @ AT^T, bf16 MFMA, 128x64 tile, K split x4 ----------
__global__ __launch_bounds__(256) void k_gemm_t(const __hip_bfloat16* __restrict__ X,
                                                const __hip_bfloat16* __restrict__ AT,
                                                float* __restrict__ tp) {
  __shared__ __hip_bfloat16 As[128][32];
  __shared__ __hip_bfloat16 Bs[64][32];
  const int tid = threadIdx.x;
  const int wave = tid >> 6, lane = tid & 63;
  const int g = lane >> 4, c16 = lane & 15;
  const int m0 = blockIdx.x * 128;
  const int kc = blockIdx.y;                 // K chunk of 512
  const int wm = (wave >> 1) * 64, wn = (wave & 1) * 32;
  f32x4 acc[4][2] = {};
  const int scol = (lane & 3) * 8;
  const __hip_bfloat16* ga = X  + (size_t)(m0 + wave * 32 + (lane >> 2)) * HDIM + scol;
  const __hip_bfloat16* gb = AT + (size_t)(wave * 16 + (lane >> 2)) * HDIM + scol;
  for (int k0 = kc * 512; k0 < kc * 512 + 512; k0 += 32) {
    __syncthreads();
    gload_lds16(ga + k0,             &As[wave * 32][0]);
    gload_lds16(ga + k0 + 16 * HDIM, &As[wave * 32 + 16][0]);
    gload_lds16(gb + k0,             &Bs[wave * 16][0]);
    __syncthreads();
    bf16x8 af[4], bfr[2];
#pragma unroll
    for (int i = 0; i < 4; ++i) af[i]  = *(const bf16x8*)&As[wm + i * 16 + c16][g * 8];
#pragma unroll
    for (int j = 0; j < 2; ++j) bfr[j] = *(const bf16x8*)&Bs[wn + j * 16 + c16][g * 8];
#pragma unroll
    for (int i = 0; i < 4; ++i)
#pragma unroll
      for (int j = 0; j < 2; ++j)
        acc[i][j] = __builtin_amdgcn_mfma_f32_16x16x32_bf16(af[i], bfr[j], acc[i][j], 0, 0, 0);
  }
#pragma unroll
  for (int i = 0; i < 4; ++i)
#pragma unroll
    for (int j = 0; j < 2; ++j)
#pragma unroll
      for (int r = 0; r < 4; ++r) {
        int row = m0 + wm + i * 16 + g * 4 + r;
        int col = wn + j * 16 + c16;
        tp[((size_t)kc * NROWS + row) * 64 + col] = acc[i][j][r];
      }
}

// ---------- K5b: c[n][er] = (sum_kc tp) * w[n][er>>3], in place over tp chunk 0 ----------
__global__ __launch_bounds__(256) void k_combine(float* __restrict__ tp,
                                                 const float* __restrict__ wgt) {
  size_t i = ((size_t)blockIdx.x * 256 + threadIdx.x) * 4;
  const size_t CH = (size_t)NROWS * 64;
  f32x4 s = *(const f32x4*)(tp + i);
  s += *(const f32x4*)(tp + i + CH);
  s += *(const f32x4*)(tp + i + 2 * CH);
  s += *(const f32x4*)(tp + i + 3 * CH);
  size_t n = i >> 6;
  int er = (int)(i & 63);
  float w = wgt[n * EXP + (er >> 3)];
  *(f32x4*)(tp + i) = s * w;
}

// ---------- K6: out[n][h] = sum_er c[n][er] * B[er][h], fp32 VALU ----------
__global__ __launch_bounds__(256) void k_final(const float* __restrict__ c,
                                               const float* __restrict__ Bm,
                                               float* __restrict__ out) {
  __shared__ float cs[32][64];
  const int t = threadIdx.x;
  const int n0 = (blockIdx.x >> 3) * 32;
  const int col0 = (blockIdx.x & 7) * 256;
  {
    int idx = t * 8;
    const float* src = c + (size_t)n0 * 64 + idx;
    *(f32x4*)&cs[idx >> 6][idx & 63] = *(const f32x4*)src;
    *(f32x4*)&cs[(idx + 4) >> 6][(idx + 4) & 63] = *(const f32x4*)(src + 4);
  }
  __syncthreads();
  const int rg = t >> 5;
  const int cg = t & 31;
  const int cc = col0 + cg * 8;
  f32x4 acc0[4] = {}, acc1[4] = {};
#pragma unroll 4
  for (int er = 0; er < 64; ++er) {
    f32x4 b0  = *(const f32x4*)&Bm[(size_t)er * HDIM + cc];
    f32x4 b1v = *(const f32x4*)&Bm[(size_t)er * HDIM + cc + 4];
#pragma unroll
    for (int r = 0; r < 4; ++r) {
      float cv = cs[rg * 4 + r][er];
      acc0[r] += cv * b0;
      acc1[r] += cv * b1v;
    }
  }
#pragma unroll
  for (int r = 0; r < 4; ++r) {
    size_t o = (size_t)(n0 + rg * 4 + r) * HDIM + cc;
    *(f32x4*)&out[o] = acc0[r];
    *(f32x4*)&out[o + 4] = acc1[r];
  }
}

extern "C" void kernel_launch(void* const* d_in, const int* in_sizes, int n_in,
                              void* d_out, int out_size, void* d_ws, size_t ws_size,
                              hipStream_t stream) {
  const float* x  = (const float*)d_in[0];
  const float* W1 = (const float*)d_in[1];
  const float* b1 = (const float*)d_in[2];
  const float* W2 = (const float*)d_in[3];
  const float* b2 = (const float*)d_in[4];
  const float* A  = (const float*)d_in[5];
  const float* B  = (const float*)d_in[6];
  float* out = (float*)d_out;

  char* ws = (char*)d_ws;
  // ws layout (bytes):
  //   xb   [8192*2048] bf16 : 33,554,432
  //   w1t  [2048*2048] bf16 :  8,388,608
  //   plog [8*8192*8]  f32  :  2,097,152
  //   at   [64*2048]   bf16 :    262,144
  //   wgt  [8192*8]    f32  :    262,144
  //   tp   [4*8192*64] f32  :  8,388,608
  __hip_bfloat16* xb  = (__hip_bfloat16*)(ws);
  __hip_bfloat16* w1t = (__hip_bfloat16*)(ws + 33554432);
  float* plog         = (float*)(ws + 41943040);
  __hip_bfloat16* at  = (__hip_bfloat16*)(ws + 75497472);
  float* wgt          = (float*)(ws + 75759616);
  float* tp           = (float*)(ws + 76021760);
  if (ws_size < 84410368) return;  // insufficient scratch -> fail loudly

  hipFuncSetAttribute((const void*)k_gemm_h8,
                      hipFuncAttributeMaxDynamicSharedMemorySize, 131072);

  k_cast_bf16<<<NROWS * HDIM / (256 * 8), 256, 0, stream>>>(x, xb);
  k_transcast<<<dim3(HDIM / 64, HDIM / 64), 256, 0, stream>>>(W1, w1t);
  k_cast_A<<<EXP * 8, 256, 0, stream>>>(A, at);
  k_gemm_h8<<<dim3(HDIM / 256, NROWS / 256), 512, 131072, stream>>>(xb, w1t, b1, W2, plog);
  k_softmax<<<NROWS / 256, 256, 0, stream>>>(plog, b2, wgt);
  k_gemm_t<<<dim3(NROWS / 128, 4), 256, 0, stream>>>(xb, at, tp);
  k_combine<<<NROWS * 64 / (256 * 4), 256, 0, stream>>>(tp, wgt);
  k_final<<<2048, 256, 0, stream>>>(tp /*=c*/, B, out);
}

// Round 7
// 146.094 us; speedup vs baseline: 1.9761x; 1.0697x over previous
//
#include <hip/hip_runtime.h>
#include <hip/hip_bf16.h>

// Problem constants (fixed by reference)
#define NROWS 8192
#define HDIM  2048
#define EXP   8
#define RANK  8

typedef float  f32x4  __attribute__((ext_vector_type(4)));
typedef __bf16 bf16x8 __attribute__((ext_vector_type(8)));

// async global->LDS, 16B per lane; LDS dest must be wave-uniform (HW: base + lane*16)
__device__ __forceinline__ void gload_lds16(const void* g, void* l) {
  __builtin_amdgcn_global_load_lds((const __attribute__((address_space(1))) void*)g,
                                   (__attribute__((address_space(3))) void*)l, 16, 0, 0);
}

#define FENCE asm volatile("" ::: "memory")
// mid-phase sync: staged data (issued >=7 issues ago per ledger) is visible to all waves
#define SYNC_MID6 do { FENCE; asm volatile("s_waitcnt vmcnt(6)" ::: "memory"); \
  __builtin_amdgcn_s_barrier(); __builtin_amdgcn_sched_barrier(0); FENCE; } while (0)
// end-phase sync: all waves' LDS reads of this phase are done
#define SYNC_END do { FENCE; __builtin_amdgcn_sched_barrier(0); \
  __builtin_amdgcn_s_barrier(); __builtin_amdgcn_sched_barrier(0); FENCE; } while (0)

// ---------- K1: elementwise f32 -> bf16 cast (x) ----------
__global__ __launch_bounds__(256) void k_cast_bf16(const float* __restrict__ src,
                                                   __hip_bfloat16* __restrict__ dst) {
  size_t i = ((size_t)blockIdx.x * 256 + threadIdx.x) * 8;
  float4 a = *(const float4*)(src + i);
  float4 b = *(const float4*)(src + i + 4);
  union { __hip_bfloat16 h[8]; int4 v; } u;
  u.h[0] = __float2bfloat16(a.x); u.h[1] = __float2bfloat16(a.y);
  u.h[2] = __float2bfloat16(a.z); u.h[3] = __float2bfloat16(a.w);
  u.h[4] = __float2bfloat16(b.x); u.h[5] = __float2bfloat16(b.y);
  u.h[6] = __float2bfloat16(b.z); u.h[7] = __float2bfloat16(b.w);
  *(int4*)(dst + i) = u.v;
}

// ---------- K2: W1 [k][n] f32 -> W1T [n][k] bf16 (LDS-tiled transpose) ----------
__global__ __launch_bounds__(256) void k_transcast(const float* __restrict__ W,
                                                   __hip_bfloat16* __restrict__ WT) {
  __shared__ float s[64][65];
  int n0 = blockIdx.x * 64, k0 = blockIdx.y * 64;
  for (int i = 0; i < 16; ++i) {
    int idx = threadIdx.x + i * 256;
    int r = idx >> 6, c = idx & 63;
    s[r][c] = W[(size_t)(k0 + r) * HDIM + n0 + c];
  }
  __syncthreads();
  for (int i = 0; i < 16; ++i) {
    int idx = threadIdx.x + i * 256;
    int r = idx >> 6, c = idx & 63;
    WT[(size_t)(n0 + r) * HDIM + k0 + c] = __float2bfloat16(s[c][r]);
  }
}

// ---------- K2b: A [E][H][R] f32 -> AT [E*R][H] bf16 ----------
__global__ __launch_bounds__(256) void k_cast_A(const float* __restrict__ A,
                                                __hip_bfloat16* __restrict__ AT) {
  __shared__ float s[2048];                      // 256 h x 8 r
  int e = blockIdx.x >> 3, ht = blockIdx.x & 7;
  const float* src = A + (size_t)e * (HDIM * RANK) + (size_t)ht * 256 * RANK;
  for (int i = 0; i < 8; ++i) s[threadIdx.x + i * 256] = src[threadIdx.x + i * 256];
  __syncthreads();
  for (int i = 0; i < 8; ++i) {
    int idx = threadIdx.x + i * 256;
    int r = idx >> 8, hh = idx & 255;
    AT[(size_t)(e * RANK + r) * HDIM + ht * 256 + hh] = __float2bfloat16(s[hh * 8 + r]);
  }
}

// ---------- K3: h = relu(x @ W1 + b1) + router logit partials + t = x @ A ----------
// 256x256 8-phase MFMA, 8 waves (2Mx4N), BK=64, 144KB LDS (A 64K + B 64K + T 16K),
// 3-bit row-XOR swizzle (SQ_LDS_BANK_CONFLICT=0 verified R4), bijective XCD swizzle,
// counted vmcnt(6), setprio.
// NEW vs R5: t-GEMM fused. Block (rb,cb) computes t[m0+cb*32..+32, 0:64] using the
// X tiles it already stages (disjoint row slices across cb -> no races). AT tile
// (64x64, 8KB) staged dbuf at P3; 2 extra MFMA/wave in P4 (was the empty phase).
// vmcnt ledger (issues/tile = 9: P1 Alo' 2, P2 Ahi' 2, P3 Blo'' 2 + T' 1, P4 Bhi'' 2):
//   P1 reads Alo(t)a/Ahi(t)a: 7th/11th-newest at P4(t-1) MID  -> vmcnt(6) OK
//   P3 reads Alo(t)b/Ahi(t)b: >=9-newest at P2(t) MID         -> OK
//   P4 reads T(t) (9-newest) + any A(t) gload (>=11) at P3(t) MID -> OK
// (T's insertion also fixes R5's thin race: Ahi(t)a was exactly 6th-newest before.)
__global__ __launch_bounds__(512, 2) void k_gemm_h8(const __hip_bfloat16* __restrict__ X,
                                                    const __hip_bfloat16* __restrict__ WT,
                                                    const float* __restrict__ b1,
                                                    const float* __restrict__ W2,
                                                    const __hip_bfloat16* __restrict__ AT,
                                                    float* __restrict__ plog,
                                                    float* __restrict__ tmat) {
  extern __shared__ char lds[];
  char* ldsA = lds;                 // [2 buf][2 half][128 rows][64 k] bf16 = 64KB
  char* ldsB = lds + 65536;         // same
  char* ldsT = lds + 131072;        // [2 buf][64 rows][64 k] bf16 = 16KB
  const int tid = threadIdx.x;
  const int wid = tid >> 6, lane = tid & 63;
  const int wr = wid >> 2, wc = wid & 3;        // 2 x 4 wave grid
  const int g = lane >> 4, c16 = lane & 15;
  const int xm = (c16 & 7) << 4;                // read-side swizzle XOR (3 row bits -> chunk)
  const int lin = blockIdx.y * 8 + blockIdx.x;  // gridDim.x == 8
  const int nid = (lin & 7) * 32 + (lin >> 3);  // bijective XCD remap (256 % 8 == 0)
  const int cb = nid & 7, rb = nid >> 3;
  const int m0 = rb * 256, n0 = cb * 256;
  const int NT = HDIM / 64;                     // 32 K-tiles

  // stage-source geometry (inverse swizzle: logical chunk = phys chunk ^ (row&7))
  int srow[2], scol[2];
#pragma unroll
  for (int q = 0; q < 2; ++q) {
    int L = (q * 512 + tid) * 16;               // linear phys byte within 16KB half
    int row = L >> 7;
    int chunkp = (L >> 4) & 7;
    srow[q] = row;
    scol[q] = (chunkp ^ (row & 7)) << 3;        // bf16 elements (chunk*8)
  }
  auto stage = [&](const __hip_bfloat16* gb, int rowBase, int kBase, char* half) {
    gload_lds16(gb + (size_t)(rowBase + srow[0]) * HDIM + kBase + scol[0], half + tid * 16);
    gload_lds16(gb + (size_t)(rowBase + srow[1]) * HDIM + kBase + scol[1], half + 8192 + tid * 16);
  };
  // T stage: 8KB = 512 threads x 16B (one gload each); same row-XOR pre-swizzle
  auto stageT = [&](int kBase, char* dstT) {
    int row = tid >> 3;
    int col = (((tid & 7) ^ (row & 7)) << 3);
    gload_lds16(AT + (size_t)row * HDIM + kBase + col, dstT + tid * 16);
  };
  auto ldA = [&](int b, int fr, int ks) -> bf16x8 {
    int byte = (((fr << 4) + c16) << 7) + (ks << 6) + (g << 4);
    return *(const bf16x8*)(ldsA + b * 32768 + wr * 16384 + (byte ^ xm));
  };
  auto ldB = [&](int b, int fc, int ks) -> bf16x8 {
    int byte = (((((wc & 1) << 6) + (fc << 4) + c16)) << 7) + (ks << 6) + (g << 4);
    return *(const bf16x8*)(ldsB + b * 32768 + (wc >> 1) * 16384 + (byte ^ xm));
  };
  // t-GEMM A-operand: X row arow = cb*32 + wr*16 + c16 (row&7 == c16&7 -> same xm)
  auto ldAt = [&](int b, int ks) -> bf16x8 {
    int arow = cb * 32 + wr * 16 + c16;
    int byte = ((arow & 127) << 7) + (ks << 6) + (g << 4);
    return *(const bf16x8*)(ldsA + b * 32768 + (arow >> 7) * 16384 + (byte ^ xm));
  };
  // t-GEMM B-operand: AT row er = wc*16 + c16
  auto ldT = [&](int tb, int ks) -> bf16x8 {
    int byte = (((wc << 4) + c16) << 7) + (ks << 6) + (g << 4);
    return *(const bf16x8*)(ldsT + tb * 8192 + (byte ^ xm));
  };

  f32x4 acc[8][4] = {};
  f32x4 acc_t = {};

  // ---- prologue: A(0) 4, B(0) 4, T(0) 1, B(1) 4 = 13 issues; vmcnt(5) covers
  // everything through Bhi(0)b (newest-5 = T0, Blo1 x2, Bhi1 x2) ----
  stage(X,  m0,       0,  ldsA);
  stage(X,  m0 + 128, 0,  ldsA + 16384);
  stage(WT, n0,       0,  ldsB);
  stage(WT, n0 + 128, 0,  ldsB + 16384);
  stageT(0, ldsT);
  stage(WT, n0,       64, ldsB + 32768);
  stage(WT, n0 + 128, 64, ldsB + 32768 + 16384);
  FENCE; asm volatile("s_waitcnt vmcnt(5)" ::: "memory");
  __builtin_amdgcn_s_barrier();
  __builtin_amdgcn_sched_barrier(0); FENCE;

  for (int t = 0; t < NT; ++t) {
    const int b = t & 1;
    const int bn = b ^ 1;
    const int u1 = (t + 1 < NT) ? t + 1 : NT - 1; // clamped -> uniform vmcnt counts
    const int u2 = (t + 2 < NT) ? t + 2 : NT - 1;
    bf16x8 af[4][2], b01[2][2], b23[2][2];

    // ---------- P1: read A fr0-3 + B fc0-1 | stage A-lo(t+1) | MFMA q(r0-3,c0-1) ----------
#pragma unroll
    for (int fr = 0; fr < 4; ++fr)
#pragma unroll
      for (int ks = 0; ks < 2; ++ks) af[fr][ks] = ldA(b, fr, ks);
#pragma unroll
    for (int fc = 0; fc < 2; ++fc)
#pragma unroll
      for (int ks = 0; ks < 2; ++ks) b01[fc][ks] = ldB(b, fc, ks);
    stage(X, m0, u1 * 64, ldsA + bn * 32768);
    SYNC_MID6;
    __builtin_amdgcn_s_setprio(1);
#pragma unroll
    for (int fr = 0; fr < 4; ++fr)
#pragma unroll
      for (int fc = 0; fc < 2; ++fc)
#pragma unroll
        for (int ks = 0; ks < 2; ++ks)
          acc[fr][fc] = __builtin_amdgcn_mfma_f32_16x16x32_bf16(af[fr][ks], b01[fc][ks], acc[fr][fc], 0, 0, 0);
    __builtin_amdgcn_s_setprio(0);
    SYNC_END;

    // ---------- P2: read B fc2-3 | stage A-hi(t+1) | MFMA q(r0-3,c2-3) ----------
#pragma unroll
    for (int fc = 0; fc < 2; ++fc)
#pragma unroll
      for (int ks = 0; ks < 2; ++ks) b23[fc][ks] = ldB(b, fc + 2, ks);
    stage(X, m0 + 128, u1 * 64, ldsA + bn * 32768 + 16384);
    SYNC_MID6;
    __builtin_amdgcn_s_setprio(1);
#pragma unroll
    for (int fr = 0; fr < 4; ++fr)
#pragma unroll
      for (int fc = 0; fc < 2; ++fc)
#pragma unroll
        for (int ks = 0; ks < 2; ++ks)
          acc[fr][fc + 2] = __builtin_amdgcn_mfma_f32_16x16x32_bf16(af[fr][ks], b23[fc][ks], acc[fr][fc + 2], 0, 0, 0);
    __builtin_amdgcn_s_setprio(0);
    SYNC_END;

    // ---------- P3: read A fr4-7 | stage B-lo(t+2), T(t+1) | MFMA q(r4-7,c2-3) ----------
#pragma unroll
    for (int fr = 0; fr < 4; ++fr)
#pragma unroll
      for (int ks = 0; ks < 2; ++ks) af[fr][ks] = ldA(b, fr + 4, ks);
    stage(WT, n0, u2 * 64, ldsB + b * 32768);
    stageT(u1 * 64, ldsT + bn * 8192);
    SYNC_MID6;
    __builtin_amdgcn_s_setprio(1);
#pragma unroll
    for (int fr = 0; fr < 4; ++fr)
#pragma unroll
      for (int fc = 0; fc < 2; ++fc)
#pragma unroll
        for (int ks = 0; ks < 2; ++ks)
          acc[fr + 4][fc + 2] = __builtin_amdgcn_mfma_f32_16x16x32_bf16(af[fr][ks], b23[fc][ks], acc[fr + 4][fc + 2], 0, 0, 0);
    __builtin_amdgcn_s_setprio(0);
    SYNC_END;

    // ---------- P4: read t-frags | stage B-hi(t+2) | MFMA q(r4-7,c0-1) + 2 t-MFMA ----------
    bf16x8 ta0 = ldAt(b, 0), ta1 = ldAt(b, 1);
    bf16x8 tb0 = ldT(b, 0),  tb1 = ldT(b, 1);
    stage(WT, n0 + 128, u2 * 64, ldsB + b * 32768 + 16384);
    SYNC_MID6;
    __builtin_amdgcn_s_setprio(1);
#pragma unroll
    for (int fr = 0; fr < 4; ++fr)
#pragma unroll
      for (int fc = 0; fc < 2; ++fc)
#pragma unroll
        for (int ks = 0; ks < 2; ++ks)
          acc[fr + 4][fc] = __builtin_amdgcn_mfma_f32_16x16x32_bf16(af[fr][ks], b01[fc][ks], acc[fr + 4][fc], 0, 0, 0);
    acc_t = __builtin_amdgcn_mfma_f32_16x16x32_bf16(ta0, tb0, acc_t, 0, 0, 0);
    acc_t = __builtin_amdgcn_mfma_f32_16x16x32_bf16(ta1, tb1, acc_t, 0, 0, 0);
    __builtin_amdgcn_s_setprio(0);
    SYNC_END;
  }

  // ---- t write: block's disjoint 32-row slice; D: col=c16 (er), row=g*4+q ----
  {
    int trow = m0 + cb * 32 + wr * 16 + g * 4;
    int er = wc * 16 + c16;
#pragma unroll
    for (int q = 0; q < 4; ++q)
      tmat[(size_t)(trow + q) * 64 + er] = acc_t[q];
  }

  // ---- fused epilogue: router logit partials via LDS transpose-reduce ----
  FENCE; asm volatile("s_waitcnt vmcnt(0)" ::: "memory");
  __builtin_amdgcn_s_barrier(); FENCE;
  float* red = (float*)lds;                      // 74KB < 144KB

  f32x4 w2lo[4], w2hi[4];
  float bias[4];
#pragma unroll
  for (int fc = 0; fc < 4; ++fc) {
    int col = n0 + wc * 64 + fc * 16 + c16;
    const float* wp = W2 + (size_t)col * EXP;
    w2lo[fc] = *(const f32x4*)wp;
    w2hi[fc] = *(const f32x4*)(wp + 4);
    bias[fc] = b1[col];
  }
  const int oidx = tid >> 1, prt = tid & 1;
  const int rrl = oidx >> 3, re = oidx & 7;      // reader's (rloc, e)
  for (int fr = 0; fr < 8; ++fr) {
#pragma unroll
    for (int r = 0; r < 4; ++r) {
      f32x4 p0 = {}, p1 = {};
#pragma unroll
      for (int fc = 0; fc < 4; ++fc) {
        float v = acc[fr][fc][r] + bias[fc];
        v = v > 0.f ? v : 0.f;                   // f32 h (no bf16 round-trip)
        p0 += v * w2lo[fc];
        p1 += v * w2hi[fc];
      }
      int base = (wc * 16 + c16) * 289 + (wr * 16 + g * 4 + r) * 9;
#pragma unroll
      for (int e = 0; e < 4; ++e) { red[base + e] = p0[e]; red[base + 4 + e] = p1[e]; }
    }
    __syncthreads();
    {
      float s = 0.f;
#pragma unroll
      for (int wq = 0; wq < 4; ++wq)
#pragma unroll
        for (int i = 0; i < 8; ++i)
          s += red[(wq * 16 + prt * 8 + i) * 289 + rrl * 9 + re];
      s += __shfl_xor(s, 1, 64);                 // combine prt halves
      if (prt == 0) {
        int grow = (rrl >> 4) * 128 + fr * 16 + (rrl & 15);
        plog[((size_t)cb * NROWS + m0 + grow) * 8 + re] = s;
      }
    }
    __syncthreads();
  }
}

// ---------- K4: logits = sum_cb plog + b2 -> softmax -> wgt ----------
__global__ __launch_bounds__(256) void k_softmax(const float* __restrict__ plog,
                                                 const float* __restrict__ b2,
                                                 float* __restrict__ wgt) {
  int n = blockIdx.x * 256 + threadIdx.x;
  f32x4 lo = *(const f32x4*)b2, hi = *(const f32x4*)(b2 + 4);
#pragma unroll
  for (int cbk = 0; cbk < 8; ++cbk) {
    const float* p = plog + ((size_t)cbk * NROWS + n) * 8;
    lo += *(const f32x4*)p;
    hi += *(const f32x4*)(p + 4);
  }
  float m = lo[0];
#pragma unroll
  for (int q = 1; q < 4; ++q) m = fmaxf(m, lo[q]);
#pragma unroll
  for (int q = 0; q < 4; ++q) m = fmaxf(m, hi[q]);
  float s = 0.f;
#pragma unroll
  for (int q = 0; q < 4; ++q) { lo[q] = __expf(lo[q] - m); s += lo[q]; }
#pragma unroll
  for (int q = 0; q < 4; ++q) { hi[q] = __expf(hi[q] - m); s += hi[q]; }
  float inv = 1.f / s;
  *(f32x4*)&wgt[(size_t)n * 8]     = lo * inv;
  *(f32x4*)&wgt[(size_t)n * 8 + 4] = hi * inv;
}

// ---------- K6: out[n][h] = sum_er (t[n][er]*w[n][er>>3]) * B[er][h] ----------
// weighting fused into the cs load (t is raw x@A now)
__global__ __launch_bounds__(256) void k_final(const float* __restrict__ tmat,
                                               const float* __restrict__ wgt,
                                               const float* __restrict__ Bm,
                                               float* __restrict__ out) {
  __shared__ float cs[32][64];
  const int t = threadIdx.x;
  const int n0 = (blockIdx.x >> 3) * 32;
  const int col0 = (blockIdx.x & 7) * 256;
  {
    int idx = t * 8;
    int row = idx >> 6, er0 = idx & 63;          // er0 multiple of 8 -> one expert
    const float* src = tmat + (size_t)(n0 + row) * 64 + er0;
    float w = wgt[(size_t)(n0 + row) * 8 + (er0 >> 3)];
    *(f32x4*)&cs[row][er0]     = *(const f32x4*)src * w;
    *(f32x4*)&cs[row][er0 + 4] = *(const f32x4*)(src + 4) * w;
  }
  __syncthreads();
  const int rg = t >> 5;
  const int cg = t & 31;
  const int cc = col0 + cg * 8;
  f32x4 acc0[4] = {}, acc1[4] = {};
#pragma unroll 4
  for (int er = 0; er < 64; ++er) {
    f32x4 b0  = *(const f32x4*)&Bm[(size_t)er * HDIM + cc];
    f32x4 b1v = *(const f32x4*)&Bm[(size_t)er * HDIM + cc + 4];
#pragma unroll
    for (int r = 0; r < 4; ++r) {
      float cv = cs[rg * 4 + r][er];
      acc0[r] += cv * b0;
      acc1[r] += cv * b1v;
    }
  }
#pragma unroll
  for (int r = 0; r < 4; ++r) {
    size_t o = (size_t)(n0 + rg * 4 + r) * HDIM + cc;
    *(f32x4*)&out[o] = acc0[r];
    *(f32x4*)&out[o + 4] = acc1[r];
  }
}

extern "C" void kernel_launch(void* const* d_in, const int* in_sizes, int n_in,
                              void* d_out, int out_size, void* d_ws, size_t ws_size,
                              hipStream_t stream) {
  const float* x  = (const float*)d_in[0];
  const float* W1 = (const float*)d_in[1];
  const float* b1 = (const float*)d_in[2];
  const float* W2 = (const float*)d_in[3];
  const float* b2 = (const float*)d_in[4];
  const float* A  = (const float*)d_in[5];
  const float* B  = (const float*)d_in[6];
  float* out = (float*)d_out;

  char* ws = (char*)d_ws;
  // ws layout (bytes):
  //   xb   [8192*2048] bf16 : 33,554,432
  //   w1t  [2048*2048] bf16 :  8,388,608
  //   plog [8*8192*8]  f32  :  2,097,152
  //   at   [64*2048]   bf16 :    262,144
  //   wgt  [8192*8]    f32  :    262,144
  //   tmat [8192*64]   f32  :  2,097,152
  __hip_bfloat16* xb  = (__hip_bfloat16*)(ws);
  __hip_bfloat16* w1t = (__hip_bfloat16*)(ws + 33554432);
  float* plog         = (float*)(ws + 41943040);
  __hip_bfloat16* at  = (__hip_bfloat16*)(ws + 75497472);
  float* wgt          = (float*)(ws + 75759616);
  float* tmat         = (float*)(ws + 76021760);
  if (ws_size < 84410368) return;  // insufficient scratch -> fail loudly

  hipFuncSetAttribute((const void*)k_gemm_h8,
                      hipFuncAttributeMaxDynamicSharedMemorySize, 147456);

  k_cast_bf16<<<NROWS * HDIM / (256 * 8), 256, 0, stream>>>(x, xb);
  k_transcast<<<dim3(HDIM / 64, HDIM / 64), 256, 0, stream>>>(W1, w1t);
  k_cast_A<<<EXP * 8, 256, 0, stream>>>(A, at);
  k_gemm_h8<<<dim3(HDIM / 256, NROWS / 256), 512, 147456, stream>>>(xb, w1t, b1, W2, at, plog, tmat);
  k_softmax<<<NROWS / 256, 256, 0, stream>>>(plog, b2, wgt);
  k_final<<<2048, 256, 0, stream>>>(tmat, wgt, B, out);
}

// Round 8
// 140.450 us; speedup vs baseline: 2.0555x; 1.0402x over previous
//
#include <hip/hip_runtime.h>
#include <hip/hip_bf16.h>

// Problem constants (fixed by reference)
#define NROWS 8192
#define HDIM  2048
#define EXP   8
#define RANK  8

typedef float  f32x4  __attribute__((ext_vector_type(4)));
typedef __bf16 bf16x8 __attribute__((ext_vector_type(8)));

// async global->LDS, 16B per lane; LDS dest must be wave-uniform (HW: base + lane*16)
__device__ __forceinline__ void gload_lds16(const void* g, void* l) {
  __builtin_amdgcn_global_load_lds((const __attribute__((address_space(1))) void*)g,
                                   (__attribute__((address_space(3))) void*)l, 16, 0, 0);
}

#define FENCE asm volatile("" ::: "memory")
// P1 mid-phase sync: single per-tile counted wait. FIFO ledger (9 issues/tile:
// P1 Alo' 2, P2 Ahi' 2, P3 Blo''2+T' 1, P4 Bhi'' 2): newest load tile t needs is
// T(t) (issued P3(t-1)); exactly 4 younger issues exist at P1(t)-MID -> vmcnt(4).
// Each wave drains ITS OWN loads, then the barrier makes all waves' LDS writes
// collectively visible for the whole tile (P2-P4 need no further vmcnt).
#define SYNC_P1 do { FENCE; asm volatile("s_waitcnt vmcnt(4)" ::: "memory"); \
  __builtin_amdgcn_s_barrier(); __builtin_amdgcn_sched_barrier(0); FENCE; } while (0)
// mid-phase sync without vmcnt (visibility already established at P1)
#define SYNC_MIDB do { FENCE; __builtin_amdgcn_s_barrier(); \
  __builtin_amdgcn_sched_barrier(0); FENCE; } while (0)
// end-phase sync: all waves' LDS reads of this phase are done
#define SYNC_END do { FENCE; __builtin_amdgcn_sched_barrier(0); \
  __builtin_amdgcn_s_barrier(); __builtin_amdgcn_sched_barrier(0); FENCE; } while (0)

// ---------- K1: merged prep (x cast | W1 transpose-cast | A transpose-cast) ----------
__global__ __launch_bounds__(256) void k_prep(const float* __restrict__ x,
                                              const float* __restrict__ W1,
                                              const float* __restrict__ A,
                                              __hip_bfloat16* __restrict__ xb,
                                              __hip_bfloat16* __restrict__ w1t,
                                              __hip_bfloat16* __restrict__ at) {
  __shared__ float s[64][65];
  const int bid = blockIdx.x;
  if (bid < 8192) {
    // x f32 -> bf16, 8 elems/thread
    size_t i = ((size_t)bid * 256 + threadIdx.x) * 8;
    float4 a = *(const float4*)(x + i);
    float4 b = *(const float4*)(x + i + 4);
    union { __hip_bfloat16 h[8]; int4 v; } u;
    u.h[0] = __float2bfloat16(a.x); u.h[1] = __float2bfloat16(a.y);
    u.h[2] = __float2bfloat16(a.z); u.h[3] = __float2bfloat16(a.w);
    u.h[4] = __float2bfloat16(b.x); u.h[5] = __float2bfloat16(b.y);
    u.h[6] = __float2bfloat16(b.z); u.h[7] = __float2bfloat16(b.w);
    *(int4*)(xb + i) = u.v;
  } else if (bid < 9216) {
    // W1 [k][n] -> W1T [n][k] bf16, 64x64 LDS tile
    int b = bid - 8192;
    int n0 = (b & 31) * 64, k0 = (b >> 5) * 64;
    for (int i = 0; i < 16; ++i) {
      int idx = threadIdx.x + i * 256;
      int r = idx >> 6, c = idx & 63;
      s[r][c] = W1[(size_t)(k0 + r) * HDIM + n0 + c];
    }
    __syncthreads();
    for (int i = 0; i < 16; ++i) {
      int idx = threadIdx.x + i * 256;
      int r = idx >> 6, c = idx & 63;
      w1t[(size_t)(n0 + r) * HDIM + k0 + c] = __float2bfloat16(s[c][r]);
    }
  } else {
    // A [E][H][R] -> AT [E*R][H] bf16
    int b = bid - 9216;
    int e = b >> 3, ht = b & 7;
    float* sf = &s[0][0];
    const float* src = A + (size_t)e * (HDIM * RANK) + (size_t)ht * 256 * RANK;
    for (int i = 0; i < 8; ++i) sf[threadIdx.x + i * 256] = src[threadIdx.x + i * 256];
    __syncthreads();
    for (int i = 0; i < 8; ++i) {
      int idx = threadIdx.x + i * 256;
      int r = idx >> 8, hh = idx & 255;
      at[(size_t)(e * RANK + r) * HDIM + ht * 256 + hh] = __float2bfloat16(sf[hh * 8 + r]);
    }
  }
}

// ---------- K3: h = relu(x @ W1 + b1) + router logit partials + t = x @ A ----------
// 256x256 8-phase MFMA, 8 waves (2Mx4N), BK=64, 144KB LDS (A 64K + B 64K + T 16K),
// 3-bit row-XOR swizzle (SQ_LDS_BANK_CONFLICT=0 verified R4), bijective XCD swizzle,
// setprio. R7 change: ONE vmcnt(4) per K-tile at P1 (m201 discipline: never drain
// mid-tile); P2-P4 barriers only. Ledger in SYNC_P1 comment; prologue vmcnt(5)
// covers A(0)/B(0), P1(0)'s vmcnt(4) covers T(0)/B(1).
__global__ __launch_bounds__(512, 2) void k_gemm_h8(const __hip_bfloat16* __restrict__ X,
                                                    const __hip_bfloat16* __restrict__ WT,
                                                    const float* __restrict__ b1,
                                                    const float* __restrict__ W2,
                                                    const __hip_bfloat16* __restrict__ AT,
                                                    float* __restrict__ plog,
                                                    float* __restrict__ tmat) {
  extern __shared__ char lds[];
  char* ldsA = lds;                 // [2 buf][2 half][128 rows][64 k] bf16 = 64KB
  char* ldsB = lds + 65536;         // same
  char* ldsT = lds + 131072;        // [2 buf][64 rows][64 k] bf16 = 16KB
  const int tid = threadIdx.x;
  const int wid = tid >> 6, lane = tid & 63;
  const int wr = wid >> 2, wc = wid & 3;        // 2 x 4 wave grid
  const int g = lane >> 4, c16 = lane & 15;
  const int xm = (c16 & 7) << 4;                // read-side swizzle XOR (3 row bits -> chunk)
  const int lin = blockIdx.y * 8 + blockIdx.x;  // gridDim.x == 8
  const int nid = (lin & 7) * 32 + (lin >> 3);  // bijective XCD remap (256 % 8 == 0)
  const int cb = nid & 7, rb = nid >> 3;
  const int m0 = rb * 256, n0 = cb * 256;
  const int NT = HDIM / 64;                     // 32 K-tiles

  // stage-source geometry (inverse swizzle: logical chunk = phys chunk ^ (row&7))
  int srow[2], scol[2];
#pragma unroll
  for (int q = 0; q < 2; ++q) {
    int L = (q * 512 + tid) * 16;               // linear phys byte within 16KB half
    int row = L >> 7;
    int chunkp = (L >> 4) & 7;
    srow[q] = row;
    scol[q] = (chunkp ^ (row & 7)) << 3;        // bf16 elements (chunk*8)
  }
  auto stage = [&](const __hip_bfloat16* gb, int rowBase, int kBase, char* half) {
    gload_lds16(gb + (size_t)(rowBase + srow[0]) * HDIM + kBase + scol[0], half + tid * 16);
    gload_lds16(gb + (size_t)(rowBase + srow[1]) * HDIM + kBase + scol[1], half + 8192 + tid * 16);
  };
  // T stage: 8KB = 512 threads x 16B (one gload each); same row-XOR pre-swizzle
  auto stageT = [&](int kBase, char* dstT) {
    int row = tid >> 3;
    int col = (((tid & 7) ^ (row & 7)) << 3);
    gload_lds16(AT + (size_t)row * HDIM + kBase + col, dstT + tid * 16);
  };
  auto ldA = [&](int b, int fr, int ks) -> bf16x8 {
    int byte = (((fr << 4) + c16) << 7) + (ks << 6) + (g << 4);
    return *(const bf16x8*)(ldsA + b * 32768 + wr * 16384 + (byte ^ xm));
  };
  auto ldB = [&](int b, int fc, int ks) -> bf16x8 {
    int byte = (((((wc & 1) << 6) + (fc << 4) + c16)) << 7) + (ks << 6) + (g << 4);
    return *(const bf16x8*)(ldsB + b * 32768 + (wc >> 1) * 16384 + (byte ^ xm));
  };
  // t-GEMM A-operand: X row arow = cb*32 + wr*16 + c16 (row&7 == c16&7 -> same xm)
  auto ldAt = [&](int b, int ks) -> bf16x8 {
    int arow = cb * 32 + wr * 16 + c16;
    int byte = ((arow & 127) << 7) + (ks << 6) + (g << 4);
    return *(const bf16x8*)(ldsA + b * 32768 + (arow >> 7) * 16384 + (byte ^ xm));
  };
  // t-GEMM B-operand: AT row er = wc*16 + c16
  auto ldT = [&](int tb, int ks) -> bf16x8 {
    int byte = (((wc << 4) + c16) << 7) + (ks << 6) + (g << 4);
    return *(const bf16x8*)(ldsT + tb * 8192 + (byte ^ xm));
  };

  f32x4 acc[8][4] = {};
  f32x4 acc_t = {};

  // ---- prologue: A(0) 4, B(0) 4, T(0) 1, B(1) 4 = 13 issues; vmcnt(5) covers A0/B0 ----
  stage(X,  m0,       0,  ldsA);
  stage(X,  m0 + 128, 0,  ldsA + 16384);
  stage(WT, n0,       0,  ldsB);
  stage(WT, n0 + 128, 0,  ldsB + 16384);
  stageT(0, ldsT);
  stage(WT, n0,       64, ldsB + 32768);
  stage(WT, n0 + 128, 64, ldsB + 32768 + 16384);
  FENCE; asm volatile("s_waitcnt vmcnt(5)" ::: "memory");
  __builtin_amdgcn_s_barrier();
  __builtin_amdgcn_sched_barrier(0); FENCE;

  for (int t = 0; t < NT; ++t) {
    const int b = t & 1;
    const int bn = b ^ 1;
    const int u1 = (t + 1 < NT) ? t + 1 : NT - 1; // clamped -> uniform vmcnt counts
    const int u2 = (t + 2 < NT) ? t + 2 : NT - 1;
    bf16x8 af[4][2], b01[2][2], b23[2][2];

    // ---------- P1: read A fr0-3 + B fc0-1 | stage A-lo(t+1) | vmcnt(4) | MFMA q(r0-3,c0-1) ----------
#pragma unroll
    for (int fr = 0; fr < 4; ++fr)
#pragma unroll
      for (int ks = 0; ks < 2; ++ks) af[fr][ks] = ldA(b, fr, ks);
#pragma unroll
    for (int fc = 0; fc < 2; ++fc)
#pragma unroll
      for (int ks = 0; ks < 2; ++ks) b01[fc][ks] = ldB(b, fc, ks);
    stage(X, m0, u1 * 64, ldsA + bn * 32768);
    SYNC_P1;
    __builtin_amdgcn_s_setprio(1);
#pragma unroll
    for (int fr = 0; fr < 4; ++fr)
#pragma unroll
      for (int fc = 0; fc < 2; ++fc)
#pragma unroll
        for (int ks = 0; ks < 2; ++ks)
          acc[fr][fc] = __builtin_amdgcn_mfma_f32_16x16x32_bf16(af[fr][ks], b01[fc][ks], acc[fr][fc], 0, 0, 0);
    __builtin_amdgcn_s_setprio(0);
    SYNC_END;

    // ---------- P2: read B fc2-3 | stage A-hi(t+1) | MFMA q(r0-3,c2-3) ----------
#pragma unroll
    for (int fc = 0; fc < 2; ++fc)
#pragma unroll
      for (int ks = 0; ks < 2; ++ks) b23[fc][ks] = ldB(b, fc + 2, ks);
    stage(X, m0 + 128, u1 * 64, ldsA + bn * 32768 + 16384);
    SYNC_MIDB;
    __builtin_amdgcn_s_setprio(1);
#pragma unroll
    for (int fr = 0; fr < 4; ++fr)
#pragma unroll
      for (int fc = 0; fc < 2; ++fc)
#pragma unroll
        for (int ks = 0; ks < 2; ++ks)
          acc[fr][fc + 2] = __builtin_amdgcn_mfma_f32_16x16x32_bf16(af[fr][ks], b23[fc][ks], acc[fr][fc + 2], 0, 0, 0);
    __builtin_amdgcn_s_setprio(0);
    SYNC_END;

    // ---------- P3: read A fr4-7 | stage B-lo(t+2), T(t+1) | MFMA q(r4-7,c2-3) ----------
#pragma unroll
    for (int fr = 0; fr < 4; ++fr)
#pragma unroll
      for (int ks = 0; ks < 2; ++ks) af[fr][ks] = ldA(b, fr + 4, ks);
    stage(WT, n0, u2 * 64, ldsB + b * 32768);
    stageT(u1 * 64, ldsT + bn * 8192);
    SYNC_MIDB;
    __builtin_amdgcn_s_setprio(1);
#pragma unroll
    for (int fr = 0; fr < 4; ++fr)
#pragma unroll
      for (int fc = 0; fc < 2; ++fc)
#pragma unroll
        for (int ks = 0; ks < 2; ++ks)
          acc[fr + 4][fc + 2] = __builtin_amdgcn_mfma_f32_16x16x32_bf16(af[fr][ks], b23[fc][ks], acc[fr + 4][fc + 2], 0, 0, 0);
    __builtin_amdgcn_s_setprio(0);
    SYNC_END;

    // ---------- P4: read t-frags | stage B-hi(t+2) | MFMA q(r4-7,c0-1) + 2 t-MFMA ----------
    bf16x8 ta0 = ldAt(b, 0), ta1 = ldAt(b, 1);
    bf16x8 tb0 = ldT(b, 0),  tb1 = ldT(b, 1);
    stage(WT, n0 + 128, u2 * 64, ldsB + b * 32768 + 16384);
    SYNC_MIDB;
    __builtin_amdgcn_s_setprio(1);
#pragma unroll
    for (int fr = 0; fr < 4; ++fr)
#pragma unroll
      for (int fc = 0; fc < 2; ++fc)
#pragma unroll
        for (int ks = 0; ks < 2; ++ks)
          acc[fr + 4][fc] = __builtin_amdgcn_mfma_f32_16x16x32_bf16(af[fr][ks], b01[fc][ks], acc[fr + 4][fc], 0, 0, 0);
    acc_t = __builtin_amdgcn_mfma_f32_16x16x32_bf16(ta0, tb0, acc_t, 0, 0, 0);
    acc_t = __builtin_amdgcn_mfma_f32_16x16x32_bf16(ta1, tb1, acc_t, 0, 0, 0);
    __builtin_amdgcn_s_setprio(0);
    SYNC_END;
  }

  // ---- t write: block's disjoint 32-row slice; D: col=c16 (er), row=g*4+q ----
  {
    int trow = m0 + cb * 32 + wr * 16 + g * 4;
    int er = wc * 16 + c16;
#pragma unroll
    for (int q = 0; q < 4; ++q)
      tmat[(size_t)(trow + q) * 64 + er] = acc_t[q];
  }

  // ---- fused epilogue: router logit partials via LDS transpose-reduce ----
  FENCE; asm volatile("s_waitcnt vmcnt(0)" ::: "memory");
  __builtin_amdgcn_s_barrier(); FENCE;
  float* red = (float*)lds;                      // 74KB < 144KB

  f32x4 w2lo[4], w2hi[4];
  float bias[4];
#pragma unroll
  for (int fc = 0; fc < 4; ++fc) {
    int col = n0 + wc * 64 + fc * 16 + c16;
    const float* wp = W2 + (size_t)col * EXP;
    w2lo[fc] = *(const f32x4*)wp;
    w2hi[fc] = *(const f32x4*)(wp + 4);
    bias[fc] = b1[col];
  }
  const int oidx = tid >> 1, prt = tid & 1;
  const int rrl = oidx >> 3, re = oidx & 7;      // reader's (rloc, e)
  for (int fr = 0; fr < 8; ++fr) {
#pragma unroll
    for (int r = 0; r < 4; ++r) {
      f32x4 p0 = {}, p1 = {};
#pragma unroll
      for (int fc = 0; fc < 4; ++fc) {
        float v = acc[fr][fc][r] + bias[fc];
        v = v > 0.f ? v : 0.f;                   // f32 h (no bf16 round-trip)
        p0 += v * w2lo[fc];
        p1 += v * w2hi[fc];
      }
      int base = (wc * 16 + c16) * 289 + (wr * 16 + g * 4 + r) * 9;
#pragma unroll
      for (int e = 0; e < 4; ++e) { red[base + e] = p0[e]; red[base + 4 + e] = p1[e]; }
    }
    __syncthreads();
    {
      float s = 0.f;
#pragma unroll
      for (int wq = 0; wq < 4; ++wq)
#pragma unroll
        for (int i = 0; i < 8; ++i)
          s += red[(wq * 16 + prt * 8 + i) * 289 + rrl * 9 + re];
      s += __shfl_xor(s, 1, 64);                 // combine prt halves
      if (prt == 0) {
        int grow = (rrl >> 4) * 128 + fr * 16 + (rrl & 15);
        plog[((size_t)cb * NROWS + m0 + grow) * 8 + re] = s;
      }
    }
    __syncthreads();
  }
}

// ---------- K6: fused softmax + out[n][h] = sum_er (t*w) * B[er][h] ----------
// thread t owns (row = t>>3, expert e = t&7): computes softmax weight inline
// (8-lane shfl group reduce), scales its own t-chunk er0 = e*8..e*8+8. No wgt buffer.
__global__ __launch_bounds__(256) void k_final(const float* __restrict__ plog,
                                               const float* __restrict__ b2,
                                               const float* __restrict__ tmat,
                                               const float* __restrict__ Bm,
                                               float* __restrict__ out) {
  __shared__ float cs[32][64];
  const int t = threadIdx.x;
  const int n0 = (blockIdx.x >> 3) * 32;
  const int col0 = (blockIdx.x & 7) * 256;
  {
    int row = t >> 3, e = t & 7;
    float lg = b2[e];
#pragma unroll
    for (int cbk = 0; cbk < 8; ++cbk)
      lg += plog[((size_t)cbk * NROWS + n0 + row) * 8 + e];
    float m = lg;
#pragma unroll
    for (int off = 4; off; off >>= 1) m = fmaxf(m, __shfl_xor(m, off, 64));
    float ex = __expf(lg - m);
    float s = ex;
#pragma unroll
    for (int off = 4; off; off >>= 1) s += __shfl_xor(s, off, 64);
    float w = ex / s;
    const float* src = tmat + (size_t)(n0 + row) * 64 + e * 8;
    *(f32x4*)&cs[row][e * 8]     = *(const f32x4*)src * w;
    *(f32x4*)&cs[row][e * 8 + 4] = *(const f32x4*)(src + 4) * w;
  }
  __syncthreads();
  const int rg = t >> 5;
  const int cg = t & 31;
  const int cc = col0 + cg * 8;
  f32x4 acc0[4] = {}, acc1[4] = {};
#pragma unroll 4
  for (int er = 0; er < 64; ++er) {
    f32x4 b0  = *(const f32x4*)&Bm[(size_t)er * HDIM + cc];
    f32x4 b1v = *(const f32x4*)&Bm[(size_t)er * HDIM + cc + 4];
#pragma unroll
    for (int r = 0; r < 4; ++r) {
      float cv = cs[rg * 4 + r][er];
      acc0[r] += cv * b0;
      acc1[r] += cv * b1v;
    }
  }
#pragma unroll
  for (int r = 0; r < 4; ++r) {
    size_t o = (size_t)(n0 + rg * 4 + r) * HDIM + cc;
    *(f32x4*)&out[o] = acc0[r];
    *(f32x4*)&out[o + 4] = acc1[r];
  }
}

extern "C" void kernel_launch(void* const* d_in, const int* in_sizes, int n_in,
                              void* d_out, int out_size, void* d_ws, size_t ws_size,
                              hipStream_t stream) {
  const float* x  = (const float*)d_in[0];
  const float* W1 = (const float*)d_in[1];
  const float* b1 = (const float*)d_in[2];
  const float* W2 = (const float*)d_in[3];
  const float* b2 = (const float*)d_in[4];
  const float* A  = (const float*)d_in[5];
  const float* B  = (const float*)d_in[6];
  float* out = (float*)d_out;

  char* ws = (char*)d_ws;
  // ws layout (bytes):
  //   xb   [8192*2048] bf16 : 33,554,432
  //   w1t  [2048*2048] bf16 :  8,388,608
  //   plog [8*8192*8]  f32  :  2,097,152
  //   at   [64*2048]   bf16 :    262,144
  //   (unused)              :    262,144
  //   tmat [8192*64]   f32  :  2,097,152
  __hip_bfloat16* xb  = (__hip_bfloat16*)(ws);
  __hip_bfloat16* w1t = (__hip_bfloat16*)(ws + 33554432);
  float* plog         = (float*)(ws + 41943040);
  __hip_bfloat16* at  = (__hip_bfloat16*)(ws + 75497472);
  float* tmat         = (float*)(ws + 76021760);
  if (ws_size < 84410368) return;  // insufficient scratch -> fail loudly

  hipFuncSetAttribute((const void*)k_gemm_h8,
                      hipFuncAttributeMaxDynamicSharedMemorySize, 147456);

  k_prep<<<8192 + 1024 + 64, 256, 0, stream>>>(x, W1, A, xb, w1t, at);
  k_gemm_h8<<<dim3(HDIM / 256, NROWS / 256), 512, 147456, stream>>>(xb, w1t, b1, W2, at, plog, tmat);
  k_final<<<2048, 256, 0, stream>>>(plog, b2, tmat, B, out);
}